// Round 5
// baseline (219.909 us; speedup 1.0000x reference)
//
#include <hip/hip_runtime.h>
#include <hip/hip_bf16.h>
#include <stdint.h>

typedef short short8 __attribute__((ext_vector_type(8)));
typedef short short4v __attribute__((ext_vector_type(4)));
typedef float floatx4 __attribute__((ext_vector_type(4)));

#define AS1 __attribute__((address_space(1)))
#define AS3 __attribute__((address_space(3)))
#define DEV static __device__ __forceinline__

#if __has_builtin(__builtin_amdgcn_mfma_f32_16x16x16bf16_1k)
#define HAVE_MFMA16 1
#else
#define HAVE_MFMA16 0
#endif

DEV uint16_t f2bf(float x) {
  union { float f; uint32_t u; } v; v.f = x;
  return (uint16_t)((v.u + 0x7fffu + ((v.u >> 16) & 1u)) >> 16);
}

DEV uint32_t cvtpk(float a, float b) {
  uint32_t r;
  asm("v_cvt_pk_bf16_f32 %0, %1, %2" : "=v"(r) : "v"(a), "v"(b));
  return r;
}

// ---------------- prep kernels ----------------

__global__ __launch_bounds__(256) void cvt_bf16_k(const float* __restrict__ src,
                                                  uint16_t* __restrict__ dst, int n4) {
  int i = blockIdx.x * 256 + threadIdx.x;
  if (i >= n4) return;
  float4 v = ((const float4*)src)[i];
  union { uint16_t u[4]; uint64_t q; } o;
  o.u[0] = f2bf(v.x); o.u[1] = f2bf(v.y); o.u[2] = f2bf(v.z); o.u[3] = f2bf(v.w);
  ((uint64_t*)dst)[i] = o.q;
}

// WqFT[j][k] = sum_{r<4} Wq[k][128*(j>>5)+4*(j&31)+r]   (j<512, k<2048), bf16 transposed
__global__ __launch_bounds__(256) void fold_wq_t_k(const float* __restrict__ Wq,
                                                   uint16_t* __restrict__ WqFT) {
  __shared__ float tile[32][33];
  const int t = threadIdx.x;
  const int j0 = (blockIdx.x / 64) * 32, k0 = (blockIdx.x % 64) * 32;
  {
    const int tj = t & 31, tk8 = t >> 5;
    const int j = j0 + tj;
    const int base = 128 * (j >> 5) + 4 * (j & 31);
    for (int kk = 0; kk < 4; ++kk) {
      int kl = tk8 * 4 + kk;
      float4 w = *(const float4*)(Wq + (size_t)(k0 + kl) * 2048 + base);
      tile[tj][kl] = w.x + w.y + w.z + w.w;
    }
  }
  __syncthreads();
  {
    const int tk = t & 31, tj8 = t >> 5;
    for (int jj = 0; jj < 4; ++jj) {
      int jl = tj8 * 4 + jj;
      WqFT[(size_t)(j0 + jl) * 2048 + k0 + tk] = f2bf(tile[jl][tk]);
    }
  }
}

__global__ __launch_bounds__(256) void wkv_t_k(const float* __restrict__ Wk,
                                               const float* __restrict__ Wv,
                                               uint16_t* __restrict__ WkvT) {
  __shared__ float tile[32][33];
  const int t = threadIdx.x;
  const int j0 = (blockIdx.x / 64) * 32, k0 = (blockIdx.x % 64) * 32;
  const float* src = (j0 < 512) ? Wk : Wv;
  const int jb = (j0 < 512) ? j0 : j0 - 512;
  {
    const int tj = t & 31, tk8 = t >> 5;
    for (int kk = 0; kk < 4; ++kk) {
      int kl = tk8 * 4 + kk;
      tile[tj][kl] = src[(size_t)(k0 + kl) * 512 + jb + tj];
    }
  }
  __syncthreads();
  {
    const int tk = t & 31, tj8 = t >> 5;
    for (int jj = 0; jj < 4; ++jj) {
      int jl = tj8 * 4 + jj;
      WkvT[(size_t)(j0 + jl) * 2048 + k0 + tk] = f2bf(tile[jl][tk]);
    }
  }
}

__global__ __launch_bounds__(256) void wof_t_k(const float* __restrict__ Wo,
                                               uint16_t* __restrict__ WoFT) {
  __shared__ float tile[32][33];
  const int t = threadIdx.x;
  const int n0 = (blockIdx.x / 16) * 32, j0 = (blockIdx.x % 16) * 32;
  {
    const int tn = t & 31, tj8 = t >> 5;
    for (int jj = 0; jj < 4; ++jj) {
      int jl = tj8 * 4 + jj;
      int j = j0 + jl;
      int base = 128 * (j >> 5) + 4 * (j & 31);
      float ssum = 0.f;
      for (int r = 0; r < 4; ++r) ssum += Wo[(size_t)(base + r) * 2048 + n0 + tn];
      tile[tn][jl] = ssum;
    }
  }
  __syncthreads();
  {
    const int tj = t & 31, tn8 = t >> 5;
    for (int nn = 0; nn < 4; ++nn) {
      int nl = tn8 * 4 + nn;
      WoFT[(size_t)(n0 + nl) * 512 + j0 + tj] = f2bf(tile[nl][tj]);
    }
  }
}

// mask triviality flag
__global__ void flag_init_k(uint32_t* f) {
  if (threadIdx.x == 0 && blockIdx.x == 0) *f = 1u;
}
__global__ __launch_bounds__(256) void mask_scan_k(const float* __restrict__ mask,
                                                   uint32_t* __restrict__ f) {
  int i = blockIdx.x * 256 + threadIdx.x;
  const float4* p = (const float4*)mask;
  float4 a = p[i * 2], b = p[i * 2 + 1];
  bool bad = (a.x != 1.f) | (a.y != 1.f) | (a.z != 1.f) | (a.w != 1.f) |
             (b.x != 1.f) | (b.y != 1.f) | (b.z != 1.f) | (b.w != 1.f);
  if (bad) *f = 0u;
}

// ------- bf16 GEMM: C[M,N] = A[M,K] @ BT[N,K]^T, optional batch on BT/C ----------
template <typename OutT, int BM, int BN, int FA, int FB>
__global__ __launch_bounds__(256) void gemm_bt(const uint16_t* __restrict__ A,
                                               const uint16_t* __restrict__ BT,
                                               OutT* __restrict__ C, int M, int N, int K,
                                               float scale, int nbb, long sBT, long sC) {
  constexpr int BK = 64;
  __shared__ __attribute__((aligned(16))) uint16_t As[BM * BK];
  __shared__ __attribute__((aligned(16))) uint16_t Bs[BN * BK];
  const int bb = blockIdx.x / nbb, rb = blockIdx.x % nbb;
  BT += (size_t)bb * sBT;
  C += (size_t)bb * sC;
  const int nbn = N / BN;
  const int m0 = (rb / nbn) * BM;
  const int n0 = (rb % nbn) * BN;
  const int lane = threadIdx.x & 63, wave = threadIdx.x >> 6;
  const int lo = lane & 15, g = lane >> 4;
  const int wm = wave >> 1, wn = wave & 1;
  constexpr int CA = BM / 32, CB = BN / 32;
  floatx4 acc[FA][FB] = {};

  for (int k0 = 0; k0 < K; k0 += BK) {
#pragma unroll
    for (int c = 0; c < CA; ++c) {
      int slot = (wave * CA + c) * 64 + lane;
      int row = slot >> 3, col = (slot & 7) * 8;
      __builtin_amdgcn_global_load_lds((const AS1 uint32_t*)(A + (size_t)(m0 + row) * K + k0 + col),
                                       (AS3 uint32_t*)(As + (size_t)(wave * CA + c) * 512), 16, 0, 0);
    }
#pragma unroll
    for (int c = 0; c < CB; ++c) {
      int slot = (wave * CB + c) * 64 + lane;
      int row = slot >> 3, col = (slot & 7) * 8;
      __builtin_amdgcn_global_load_lds((const AS1 uint32_t*)(BT + (size_t)(n0 + row) * K + k0 + col),
                                       (AS3 uint32_t*)(Bs + (size_t)(wave * CB + c) * 512), 16, 0, 0);
    }
    __syncthreads();
#pragma unroll
    for (int kk = 0; kk < BK; kk += 32) {
      short8 af[FA], bf[FB];
#pragma unroll
      for (int fa = 0; fa < FA; ++fa)
        af[fa] = *(const short8*)&As[(wm * FA * 16 + fa * 16 + lo) * BK + kk + g * 8];
#pragma unroll
      for (int fb = 0; fb < FB; ++fb)
        bf[fb] = *(const short8*)&Bs[(wn * FB * 16 + fb * 16 + lo) * BK + kk + g * 8];
#pragma unroll
      for (int fa = 0; fa < FA; ++fa)
#pragma unroll
        for (int fb = 0; fb < FB; ++fb)
          acc[fa][fb] = __builtin_amdgcn_mfma_f32_16x16x32_bf16(af[fa], bf[fb], acc[fa][fb], 0, 0, 0);
    }
    __syncthreads();
  }
#pragma unroll
  for (int fa = 0; fa < FA; ++fa)
#pragma unroll
    for (int fb = 0; fb < FB; ++fb)
#pragma unroll
      for (int r = 0; r < 4; ++r) {
        int row = m0 + wm * FA * 16 + fa * 16 + g * 4 + r;
        int col = n0 + wn * FB * 16 + fb * 16 + lo;
        if constexpr (sizeof(OutT) == 2)
          C[(size_t)row * N + col] = (OutT)f2bf(acc[fa][fb][r] * scale);
        else
          C[(size_t)row * N + col] = (OutT)(acc[fa][fb][r] * scale);
      }
}

// ---------------- flash attention, d_eff = 32, kv-split x2, 4 waves/block ----------
// Partial (m, s, acc) per kv-half written to workspace; combine_k merges.
__global__ __launch_bounds__(256) void attn_k(const uint16_t* __restrict__ Qf,
                                              const uint16_t* __restrict__ XK,
                                              const uint16_t* __restrict__ VT,
                                              const float* __restrict__ mask,
                                              const uint32_t* __restrict__ flag,
                                              float* __restrict__ Pacc,
                                              float2* __restrict__ Pms) {
  __shared__ __attribute__((aligned(16))) uint16_t Ks[2][64 * 32];
  __shared__ __attribute__((aligned(16))) uint16_t Vs[2][32 * 64];
  const int tid = threadIdx.x;
  const int lane = tid & 63, w = tid >> 6;
  const int lo = lane & 15, g = lane >> 4;
  const int bid = blockIdx.x;
  const int lb = (bid & 7) * 256 + (bid >> 3); // XCD-chunked (2048 % 8 == 0, bijective)
  const int qt = lb & 31, h = (lb >> 5) & 15, b = (lb >> 9) & 1, half = lb >> 10;
  const int q0 = qt * 64 + w * 16;
  const int kvbase = half * 1024;
  const bool trivial = (*flag != 0u);
  const float LOG2E = 1.4426950408889634f;

  short8 qf = *(const short8*)(Qf + ((size_t)(b * 2048 + q0 + lo)) * 512 + h * 32 + g * 8);

  // K staging: slot s = w*64+lane (16B units); row=s>>2, phys chunk=s&3,
  // global chunk = phys ^ (row&3) ^ ((row>>2)&3)
  const int sK = w * 64 + lane;
  const int rK = sK >> 2;
  const int cKg = (sK & 3) ^ (rK & 3) ^ ((rK >> 2) & 3);
  const uint16_t* Ksrc = XK + ((size_t)(b * 2048 + kvbase + rK)) * 512 + h * 32 + cKg * 8;
  // V staging: row f=s>>3, phys chunk=s&7, global chunk = (phys - f)&7 (per-row rotation)
  const int fV = sK >> 3, cV = ((sK & 7) - fV) & 7;
  const uint16_t* Vsrc = VT + ((size_t)(b * 512 + h * 32 + fV)) * 2048 + kvbase + cV * 8;

  // per-lane K read offset (inverse of staging swizzle)
  const int swzL = (lo & 3) ^ ((lo >> 2) & 3);
  const int cK = (g ^ swzL) * 8;
#if !HAVE_MFMA16
  const int vA = (((g) + lo) & 7) * 8;
  const int vB = (((g + 4) + lo) & 7) * 8;
  const int srcA = lo + 16 * ((2 * g) & 3);
  const int srcB = lo + 16 * ((2 * g + 1) & 3);
#endif

  float m = -1e30f, sp = 0.f;
  floatx4 acc0 = {0.f, 0.f, 0.f, 0.f}, acc1 = {0.f, 0.f, 0.f, 0.f};
  const floatx4 zf = {0.f, 0.f, 0.f, 0.f};

  __builtin_amdgcn_global_load_lds((const AS1 uint32_t*)Ksrc,
                                   (AS3 uint32_t*)(&Ks[0][0] + w * 512), 16, 0, 0);
  __builtin_amdgcn_global_load_lds((const AS1 uint32_t*)Vsrc,
                                   (AS3 uint32_t*)(&Vs[0][0] + w * 512), 16, 0, 0);
  __syncthreads();

  int buf = 0;
  for (int t = 0; t < 16; ++t) {
    if (t < 15) {
      __builtin_amdgcn_global_load_lds((const AS1 uint32_t*)(Ksrc + (size_t)(t + 1) * 64 * 512),
                                       (AS3 uint32_t*)(&Ks[buf ^ 1][0] + w * 512), 16, 0, 0);
      __builtin_amdgcn_global_load_lds((const AS1 uint32_t*)(Vsrc + (size_t)(t + 1) * 64),
                                       (AS3 uint32_t*)(&Vs[buf ^ 1][0] + w * 512), 16, 0, 0);
    }
    const uint16_t* Kb = &Ks[buf][0];
    const uint16_t* Vb = &Vs[buf][0];
    const int k0 = kvbase + t * 64;

    short8 kf0 = *(const short8*)(Kb + (lo) * 32 + cK);
    short8 kf1 = *(const short8*)(Kb + (lo + 16) * 32 + cK);
    short8 kf2 = *(const short8*)(Kb + (lo + 32) * 32 + cK);
    short8 kf3 = *(const short8*)(Kb + (lo + 48) * 32 + cK);
    floatx4 s0 = __builtin_amdgcn_mfma_f32_16x16x32_bf16(kf0, qf, zf, 0, 0, 0);
    floatx4 s1 = __builtin_amdgcn_mfma_f32_16x16x32_bf16(kf1, qf, zf, 0, 0, 0);
    floatx4 s2 = __builtin_amdgcn_mfma_f32_16x16x32_bf16(kf2, qf, zf, 0, 0, 0);
    floatx4 s3 = __builtin_amdgcn_mfma_f32_16x16x32_bf16(kf3, qf, zf, 0, 0, 0);

    if (!trivial) {
      const float* mp = mask + (size_t)(q0 + lo) * 2048 + k0 + g * 4;
      float4 m0v = *(const float4*)(mp);
      float4 m1v = *(const float4*)(mp + 16);
      float4 m2v = *(const float4*)(mp + 32);
      float4 m3v = *(const float4*)(mp + 48);
      s0[0] -= (1.f / m0v.x - 1.f) * LOG2E; s0[1] -= (1.f / m0v.y - 1.f) * LOG2E;
      s0[2] -= (1.f / m0v.z - 1.f) * LOG2E; s0[3] -= (1.f / m0v.w - 1.f) * LOG2E;
      s1[0] -= (1.f / m1v.x - 1.f) * LOG2E; s1[1] -= (1.f / m1v.y - 1.f) * LOG2E;
      s1[2] -= (1.f / m1v.z - 1.f) * LOG2E; s1[3] -= (1.f / m1v.w - 1.f) * LOG2E;
      s2[0] -= (1.f / m2v.x - 1.f) * LOG2E; s2[1] -= (1.f / m2v.y - 1.f) * LOG2E;
      s2[2] -= (1.f / m2v.z - 1.f) * LOG2E; s2[3] -= (1.f / m2v.w - 1.f) * LOG2E;
      s3[0] -= (1.f / m3v.x - 1.f) * LOG2E; s3[1] -= (1.f / m3v.y - 1.f) * LOG2E;
      s3[2] -= (1.f / m3v.z - 1.f) * LOG2E; s3[3] -= (1.f / m3v.w - 1.f) * LOG2E;
    }

    float a0 = fmaxf(fmaxf(s0[0], s0[1]), fmaxf(s0[2], s0[3]));
    float a1 = fmaxf(fmaxf(s1[0], s1[1]), fmaxf(s1[2], s1[3]));
    float a2 = fmaxf(fmaxf(s2[0], s2[1]), fmaxf(s2[2], s2[3]));
    float a3 = fmaxf(fmaxf(s3[0], s3[1]), fmaxf(s3[2], s3[3]));
    float pmax = fmaxf(fmaxf(a0, a1), fmaxf(a2, a3));

    if (!__all(pmax - m <= 8.f)) {
      float tm = pmax;
      tm = fmaxf(tm, __shfl_xor(tm, 16));
      tm = fmaxf(tm, __shfl_xor(tm, 32));
      float mn = fmaxf(m, tm);
      float f = __builtin_amdgcn_exp2f(m - mn);
      sp *= f;
#pragma unroll
      for (int r = 0; r < 4; ++r) { acc0[r] *= f; acc1[r] *= f; }
      m = mn;
    }

    float p0[4], p1[4], p2[4], p3[4];
#pragma unroll
    for (int r = 0; r < 4; ++r) {
      p0[r] = __builtin_amdgcn_exp2f(s0[r] - m);
      p1[r] = __builtin_amdgcn_exp2f(s1[r] - m);
      p2[r] = __builtin_amdgcn_exp2f(s2[r] - m);
      p3[r] = __builtin_amdgcn_exp2f(s3[r] - m);
    }
    sp += ((p0[0] + p0[1]) + (p0[2] + p0[3])) + ((p1[0] + p1[1]) + (p1[2] + p1[3])) +
          ((p2[0] + p2[1]) + (p2[2] + p2[3])) + ((p3[0] + p3[1]) + (p3[2] + p3[3]));

#if HAVE_MFMA16
    // PV via 16x16x16: B-fragment (lane holds B[k=4g+r][j=lo]) == P's produced layout.
    // V^T A-fragment: lane (g,lo) needs Vs[f][c*16+4g+0..3]; stored chunk p=(kc+f)&7.
#pragma unroll
    for (int c = 0; c < 4; ++c) {
      const float* pc = (c == 0) ? p0 : (c == 1) ? p1 : (c == 2) ? p2 : p3;
      union { uint32_t u[2]; short4v v; } pk;
      pk.u[0] = cvtpk(pc[0], pc[1]);
      pk.u[1] = cvtpk(pc[2], pc[3]);
      const int kc = 2 * c + (g >> 1);
      const int pA = (kc + lo) & 7;
      const int pB = (kc + lo + 16) & 7;
      short4v va = *(const short4v*)(Vb + lo * 64 + pA * 8 + (g & 1) * 4);
      short4v vb = *(const short4v*)(Vb + (lo + 16) * 64 + pB * 8 + (g & 1) * 4);
      acc0 = __builtin_amdgcn_mfma_f32_16x16x16bf16_1k(va, pk.v, acc0, 0, 0, 0);
      acc1 = __builtin_amdgcn_mfma_f32_16x16x16bf16_1k(vb, pk.v, acc1, 0, 0, 0);
    }
#else
    uint32_t u0 = cvtpk(p0[0], p0[1]), u1 = cvtpk(p0[2], p0[3]);
    uint32_t u2 = cvtpk(p1[0], p1[1]), u3 = cvtpk(p1[2], p1[3]);
    uint32_t u4 = cvtpk(p2[0], p2[1]), u5 = cvtpk(p2[2], p2[3]);
    uint32_t u6 = cvtpk(p3[0], p3[1]), u7 = cvtpk(p3[2], p3[3]);
    union { uint32_t u[4]; short8 v; } pfa, pfb;
    {
      uint32_t x0 = (uint32_t)__shfl((int)u0, srcA), x2 = (uint32_t)__shfl((int)u2, srcA);
      uint32_t x1 = (uint32_t)__shfl((int)u1, srcA), x3 = (uint32_t)__shfl((int)u3, srcA);
      uint32_t y0 = (uint32_t)__shfl((int)u0, srcB), y2 = (uint32_t)__shfl((int)u2, srcB);
      uint32_t y1 = (uint32_t)__shfl((int)u1, srcB), y3 = (uint32_t)__shfl((int)u3, srcB);
      pfa.u[0] = (g < 2) ? x0 : x2;
      pfa.u[1] = (g < 2) ? x1 : x3;
      pfa.u[2] = (g < 2) ? y0 : y2;
      pfa.u[3] = (g < 2) ? y1 : y3;
    }
    {
      uint32_t x4 = (uint32_t)__shfl((int)u4, srcA), x6 = (uint32_t)__shfl((int)u6, srcA);
      uint32_t x5 = (uint32_t)__shfl((int)u5, srcA), x7 = (uint32_t)__shfl((int)u7, srcA);
      uint32_t y4 = (uint32_t)__shfl((int)u4, srcB), y6 = (uint32_t)__shfl((int)u6, srcB);
      uint32_t y5 = (uint32_t)__shfl((int)u5, srcB), y7 = (uint32_t)__shfl((int)u7, srcB);
      pfb.u[0] = (g < 2) ? x4 : x6;
      pfb.u[1] = (g < 2) ? x5 : x7;
      pfb.u[2] = (g < 2) ? y4 : y6;
      pfb.u[3] = (g < 2) ? y5 : y7;
    }
    short8 v0a = *(const short8*)(Vb + lo * 64 + vA);
    short8 v1a = *(const short8*)(Vb + (lo + 16) * 64 + vA);
    short8 v0b = *(const short8*)(Vb + lo * 64 + vB);
    short8 v1b = *(const short8*)(Vb + (lo + 16) * 64 + vB);
    acc0 = __builtin_amdgcn_mfma_f32_16x16x32_bf16(v0a, pfa.v, acc0, 0, 0, 0);
    acc1 = __builtin_amdgcn_mfma_f32_16x16x32_bf16(v1a, pfa.v, acc1, 0, 0, 0);
    acc0 = __builtin_amdgcn_mfma_f32_16x16x32_bf16(v0b, pfb.v, acc0, 0, 0, 0);
    acc1 = __builtin_amdgcn_mfma_f32_16x16x32_bf16(v1b, pfb.v, acc1, 0, 0, 0);
#endif

    __syncthreads();
    buf ^= 1;
  }
  float s = sp;
  s += __shfl_xor(s, 16);
  s += __shfl_xor(s, 32);

  const size_t qidx = ((size_t)((half * 2 + b) * 16 + h)) * 2048 + q0 + lo;
  float* pacc = Pacc + qidx * 32;
  *(floatx4*)(pacc + 4 * g) = acc0;
  *(floatx4*)(pacc + 16 + 4 * g) = acc1;
  if (g == 0) Pms[qidx] = make_float2(m, s);
}

// ---------------- combine kv-split halves -> O32 (bf16) ----------------
__global__ __launch_bounds__(256) void combine_k(const float* __restrict__ Pacc,
                                                 const float2* __restrict__ Pms,
                                                 uint16_t* __restrict__ O32) {
  const int t = blockIdx.x * 256 + threadIdx.x; // 524288 threads
  const int f4 = t & 7;
  const int qq = (t >> 3) & 2047;
  const int h = (t >> 14) & 15;
  const int b = t >> 18;
  const size_t qidx0 = ((size_t)((0 + b) * 16 + h)) * 2048 + qq;
  const size_t qidx1 = ((size_t)((2 + b) * 16 + h)) * 2048 + qq;
  float2 ms0 = Pms[qidx0], ms1 = Pms[qidx1];
  float M = fmaxf(ms0.x, ms1.x);
  float w0 = __builtin_amdgcn_exp2f(ms0.x - M);
  float w1 = __builtin_amdgcn_exp2f(ms1.x - M);
  float inv = 1.0f / (ms0.y * w0 + ms1.y * w1);
  w0 *= inv; w1 *= inv;
  float4 a0 = *(const float4*)(Pacc + qidx0 * 32 + f4 * 4);
  float4 a1 = *(const float4*)(Pacc + qidx1 * 32 + f4 * 4);
  union { uint16_t u[4]; uint64_t q; } o;
  o.u[0] = f2bf(a0.x * w0 + a1.x * w1);
  o.u[1] = f2bf(a0.y * w0 + a1.y * w1);
  o.u[2] = f2bf(a0.z * w0 + a1.z * w1);
  o.u[3] = f2bf(a0.w * w0 + a1.w * w1);
  *(uint64_t*)(O32 + ((size_t)(b * 2048 + qq)) * 512 + h * 32 + f4 * 4) = o.q;
}

// ---------------- launch ----------------
extern "C" void kernel_launch(void* const* d_in, const int* in_sizes, int n_in,
                              void* d_out, int out_size, void* d_ws, size_t ws_size,
                              hipStream_t stream) {
  const float* q    = (const float*)d_in[0];
  const float* kv   = (const float*)d_in[1];
  const float* mask = (const float*)d_in[2];
  const float* Wq   = (const float*)d_in[3];
  const float* Wk   = (const float*)d_in[4];
  const float* Wv   = (const float*)d_in[5];
  const float* Wo   = (const float*)d_in[6];

  char* ws = (char*)d_ws;
  uint16_t* qb    = (uint16_t*)(ws);                  // 16 MB (freed after Q-proj)
  uint16_t* kvb   = (uint16_t*)(ws + (16ull << 20));  // 16 MB (freed after K/V-proj)
  uint16_t* Qf    = (uint16_t*)(ws + (32ull << 20));  // 4 MB
  uint16_t* XK    = (uint16_t*)(ws + (36ull << 20));  // 4 MB
  uint16_t* VT    = (uint16_t*)(ws + (40ull << 20));  // 8 MB
  uint16_t* O32   = (uint16_t*)(ws + (48ull << 20));  // 4 MB
  uint16_t* WqFT  = (uint16_t*)(ws + (52ull << 20));  // 2 MB
  uint16_t* WkvT  = (uint16_t*)(ws + (54ull << 20));  // 4 MB
  uint16_t* WoFT  = (uint16_t*)(ws + (58ull << 20));  // 2 MB
  uint32_t* flag  = (uint32_t*)(ws + (60ull << 20));
  float*    Pacc  = (float*)(ws);                     // 16 MB, overlaps qb (dead by attn)
  float2*   Pms   = (float2*)(ws + (16ull << 20));    // 1 MB, overlaps kvb (dead by attn)

  const float SCALE2 = 0.08838834764831845f * 1.4426950408889634f;

  flag_init_k<<<1, 64, 0, stream>>>(flag);
  mask_scan_k<<<2048, 256, 0, stream>>>(mask, flag);

  cvt_bf16_k<<<8192, 256, 0, stream>>>(q, qb, 2097152);
  cvt_bf16_k<<<8192, 256, 0, stream>>>(kv, kvb, 2097152);
  fold_wq_t_k<<<1024, 256, 0, stream>>>(Wq, WqFT);
  wkv_t_k<<<2048, 256, 0, stream>>>(Wk, Wv, WkvT);
  wof_t_k<<<1024, 256, 0, stream>>>(Wo, WoFT);

  // Q projection (folded, pre-scaled): [4096,512] = qb @ WqFT^T
  gemm_bt<uint16_t, 128, 64, 4, 2><<<256, 256, 0, stream>>>(qb, WqFT, Qf, 4096, 512, 2048,
                                                            SCALE2, 256, 0, 0);
  // K projection: [4096,512] = kvb @ WkvT(K)^T
  gemm_bt<uint16_t, 128, 64, 4, 2><<<256, 256, 0, stream>>>(kvb, WkvT, XK, 4096, 512, 2048,
                                                            1.0f, 256, 0, 0);
  // V projection, written transposed: per batch, VT[b] [512, 2048] = WkvT(V) @ kvb[b]^T
  gemm_bt<uint16_t, 64, 64, 2, 2><<<512, 256, 0, stream>>>(WkvT + 512 * 2048, kvb, VT,
                                                           512, 2048, 2048, 1.0f,
                                                           256, 2048L * 2048, 512L * 2048);
  attn_k<<<2048, 256, 0, stream>>>(Qf, XK, VT, mask, flag, Pacc, Pms);
  combine_k<<<2048, 256, 0, stream>>>(Pacc, Pms, O32);
  // output: [4096,2048] fp32 = O32 @ WoFT^T
  gemm_bt<float, 128, 64, 4, 2><<<1024, 256, 0, stream>>>(O32, WoFT, (float*)d_out,
                                                          4096, 2048, 512, 1.0f, 1024, 0, 0);
}

// Round 6
// 149.564 us; speedup vs baseline: 1.4703x; 1.4703x over previous
//
#include <hip/hip_runtime.h>
#include <hip/hip_bf16.h>
#include <stdint.h>

typedef short short8 __attribute__((ext_vector_type(8)));
typedef short short4v __attribute__((ext_vector_type(4)));
typedef float floatx4 __attribute__((ext_vector_type(4)));

#define AS1 __attribute__((address_space(1)))
#define AS3 __attribute__((address_space(3)))
#define DEV static __device__ __forceinline__

#if __has_builtin(__builtin_amdgcn_mfma_f32_16x16x16bf16_1k)
#define HAVE_MFMA16 1
#else
#define HAVE_MFMA16 0
#endif

DEV uint16_t f2bf(float x) {
  union { float f; uint32_t u; } v; v.f = x;
  return (uint16_t)((v.u + 0x7fffu + ((v.u >> 16) & 1u)) >> 16);
}

DEV uint32_t cvtpk(float a, float b) {
  uint32_t r;
  asm("v_cvt_pk_bf16_f32 %0, %1, %2" : "=v"(r) : "v"(a), "v"(b));
  return r;
}

// ---------------- merged prep kernel (block-range routed) ----------------

DEV void cvt_bf16_f(const float* __restrict__ src, uint16_t* __restrict__ dst, int bid) {
  int i = bid * 256 + threadIdx.x;
  float4 v = ((const float4*)src)[i];
  union { uint16_t u[4]; uint64_t q; } o;
  o.u[0] = f2bf(v.x); o.u[1] = f2bf(v.y); o.u[2] = f2bf(v.z); o.u[3] = f2bf(v.w);
  ((uint64_t*)dst)[i] = o.q;
}

DEV void mask_scan_f(const float* __restrict__ mask, uint32_t* __restrict__ f, int bid) {
  int i = bid * 256 + threadIdx.x;
  const float4* p = (const float4*)mask;
  float4 a = p[i * 2], b = p[i * 2 + 1];
  bool bad = (a.x != 1.f) | (a.y != 1.f) | (a.z != 1.f) | (a.w != 1.f) |
             (b.x != 1.f) | (b.y != 1.f) | (b.z != 1.f) | (b.w != 1.f);
  if (bad) *f = 0u;
}

DEV void fold_wq_f(float (*tile)[33], const float* __restrict__ Wq,
                   uint16_t* __restrict__ WqFT, int bid) {
  const int t = threadIdx.x;
  const int j0 = (bid / 64) * 32, k0 = (bid % 64) * 32;
  {
    const int tj = t & 31, tk8 = t >> 5;
    const int j = j0 + tj;
    const int base = 128 * (j >> 5) + 4 * (j & 31);
    for (int kk = 0; kk < 4; ++kk) {
      int kl = tk8 * 4 + kk;
      float4 w = *(const float4*)(Wq + (size_t)(k0 + kl) * 2048 + base);
      tile[tj][kl] = w.x + w.y + w.z + w.w;
    }
  }
  __syncthreads();
  {
    const int tk = t & 31, tj8 = t >> 5;
    for (int jj = 0; jj < 4; ++jj) {
      int jl = tj8 * 4 + jj;
      WqFT[(size_t)(j0 + jl) * 2048 + k0 + tk] = f2bf(tile[jl][tk]);
    }
  }
}

DEV void wkv_t_f(float (*tile)[33], const float* __restrict__ Wk,
                 const float* __restrict__ Wv, uint16_t* __restrict__ WkvT, int bid) {
  const int t = threadIdx.x;
  const int j0 = (bid / 64) * 32, k0 = (bid % 64) * 32;
  const float* src = (j0 < 512) ? Wk : Wv;
  const int jb = (j0 < 512) ? j0 : j0 - 512;
  {
    const int tj = t & 31, tk8 = t >> 5;
    for (int kk = 0; kk < 4; ++kk) {
      int kl = tk8 * 4 + kk;
      tile[tj][kl] = src[(size_t)(k0 + kl) * 512 + jb + tj];
    }
  }
  __syncthreads();
  {
    const int tk = t & 31, tj8 = t >> 5;
    for (int jj = 0; jj < 4; ++jj) {
      int jl = tj8 * 4 + jj;
      WkvT[(size_t)(j0 + jl) * 2048 + k0 + tk] = f2bf(tile[jl][tk]);
    }
  }
}

DEV void wof_t_f(float (*tile)[33], const float* __restrict__ Wo,
                 uint16_t* __restrict__ WoFT, int bid) {
  const int t = threadIdx.x;
  const int n0 = (bid / 16) * 32, j0 = (bid % 16) * 32;
  {
    const int tn = t & 31, tj8 = t >> 5;
    for (int jj = 0; jj < 4; ++jj) {
      int jl = tj8 * 4 + jj;
      int j = j0 + jl;
      int base = 128 * (j >> 5) + 4 * (j & 31);
      float ssum = 0.f;
      for (int r = 0; r < 4; ++r) ssum += Wo[(size_t)(base + r) * 2048 + n0 + tn];
      tile[tn][jl] = ssum;
    }
  }
  __syncthreads();
  {
    const int tj = t & 31, tn8 = t >> 5;
    for (int nn = 0; nn < 4; ++nn) {
      int nl = tn8 * 4 + nn;
      WoFT[(size_t)(n0 + nl) * 512 + j0 + tj] = f2bf(tile[nl][tj]);
    }
  }
}

__global__ __launch_bounds__(256) void prep_k(const float* __restrict__ q,
                                              const float* __restrict__ kv,
                                              const float* __restrict__ mask,
                                              const float* __restrict__ Wq,
                                              const float* __restrict__ Wk,
                                              const float* __restrict__ Wv,
                                              const float* __restrict__ Wo,
                                              uint16_t* __restrict__ qb,
                                              uint16_t* __restrict__ kvb,
                                              uint16_t* __restrict__ WqFT,
                                              uint16_t* __restrict__ WkvT,
                                              uint16_t* __restrict__ WoFT,
                                              uint32_t* __restrict__ flag) {
  __shared__ float tile[32][33];
  const int bid = blockIdx.x;
  if (bid < 8192)        cvt_bf16_f(q, qb, bid);
  else if (bid < 16384)  cvt_bf16_f(kv, kvb, bid - 8192);
  else if (bid < 18432)  mask_scan_f(mask, flag, bid - 16384);
  else if (bid < 19456)  fold_wq_f(tile, Wq, WqFT, bid - 18432);
  else if (bid < 21504)  wkv_t_f(tile, Wk, Wv, WkvT, bid - 19456);
  else                   wof_t_f(tile, Wo, WoFT, bid - 21504);
}

// ------- shared device GEMM: C[M,N] = A[M,K] @ BT[N,K]^T ----------
template <typename OutT, int BM, int BN, int FA, int FB>
DEV void gemm_dev(uint16_t* __restrict__ As, uint16_t* __restrict__ Bs,
                  const uint16_t* __restrict__ A, const uint16_t* __restrict__ BT,
                  OutT* __restrict__ C, int M, int N, int K, float scale, int rb) {
  constexpr int BK = 64;
  const int nbn = N / BN;
  const int m0 = (rb / nbn) * BM;
  const int n0 = (rb % nbn) * BN;
  const int lane = threadIdx.x & 63, wave = threadIdx.x >> 6;
  const int lo = lane & 15, g = lane >> 4;
  const int wm = wave >> 1, wn = wave & 1;
  constexpr int CA = BM / 32, CB = BN / 32;
  floatx4 acc[FA][FB] = {};

  for (int k0 = 0; k0 < K; k0 += BK) {
#pragma unroll
    for (int c = 0; c < CA; ++c) {
      int slot = (wave * CA + c) * 64 + lane;
      int row = slot >> 3, col = (slot & 7) * 8;
      __builtin_amdgcn_global_load_lds((const AS1 uint32_t*)(A + (size_t)(m0 + row) * K + k0 + col),
                                       (AS3 uint32_t*)(As + (size_t)(wave * CA + c) * 512), 16, 0, 0);
    }
#pragma unroll
    for (int c = 0; c < CB; ++c) {
      int slot = (wave * CB + c) * 64 + lane;
      int row = slot >> 3, col = (slot & 7) * 8;
      __builtin_amdgcn_global_load_lds((const AS1 uint32_t*)(BT + (size_t)(n0 + row) * K + k0 + col),
                                       (AS3 uint32_t*)(Bs + (size_t)(wave * CB + c) * 512), 16, 0, 0);
    }
    __syncthreads();
#pragma unroll
    for (int kk = 0; kk < BK; kk += 32) {
      short8 af[FA], bf[FB];
#pragma unroll
      for (int fa = 0; fa < FA; ++fa)
        af[fa] = *(const short8*)&As[(wm * FA * 16 + fa * 16 + lo) * BK + kk + g * 8];
#pragma unroll
      for (int fb = 0; fb < FB; ++fb)
        bf[fb] = *(const short8*)&Bs[(wn * FB * 16 + fb * 16 + lo) * BK + kk + g * 8];
#pragma unroll
      for (int fa = 0; fa < FA; ++fa)
#pragma unroll
        for (int fb = 0; fb < FB; ++fb)
          acc[fa][fb] = __builtin_amdgcn_mfma_f32_16x16x32_bf16(af[fa], bf[fb], acc[fa][fb], 0, 0, 0);
    }
    __syncthreads();
  }
#pragma unroll
  for (int fa = 0; fa < FA; ++fa)
#pragma unroll
    for (int fb = 0; fb < FB; ++fb)
#pragma unroll
      for (int r = 0; r < 4; ++r) {
        int row = m0 + wm * FA * 16 + fa * 16 + g * 4 + r;
        int col = n0 + wn * FB * 16 + fb * 16 + lo;
        if constexpr (sizeof(OutT) == 2)
          C[(size_t)row * N + col] = (OutT)f2bf(acc[fa][fb][r] * scale);
        else
          C[(size_t)row * N + col] = (OutT)(acc[fa][fb][r] * scale);
      }
}

// merged projections: blocks [0,256) Q, [256,512) K, [512,768) V (batched)
__global__ __launch_bounds__(256) void proj_k(const uint16_t* __restrict__ qb,
                                              const uint16_t* __restrict__ kvb,
                                              const uint16_t* __restrict__ WqFT,
                                              const uint16_t* __restrict__ WkvT,
                                              uint16_t* __restrict__ Qf,
                                              uint16_t* __restrict__ XK,
                                              uint16_t* __restrict__ VT,
                                              float scale2) {
  __shared__ __attribute__((aligned(16))) uint16_t As[128 * 64];
  __shared__ __attribute__((aligned(16))) uint16_t Bs[64 * 64];
  const int bid = blockIdx.x;
  if (bid < 256) {
    gemm_dev<uint16_t, 128, 64, 4, 2>(As, Bs, qb, WqFT, Qf, 4096, 512, 2048, scale2, bid);
  } else if (bid < 512) {
    gemm_dev<uint16_t, 128, 64, 4, 2>(As, Bs, kvb, WkvT, XK, 4096, 512, 2048, 1.0f, bid - 256);
  } else {
    int r = bid - 512;
    const int b = r >> 7;
    r &= 127;
    gemm_dev<uint16_t, 128, 64, 4, 2>(As, Bs, WkvT + 512 * 2048,
                                      kvb + (size_t)b * 2048 * 2048,
                                      VT + (size_t)b * 512 * 2048,
                                      512, 2048, 2048, 1.0f, r);
  }
}

// standalone GEMM kernel (O-projection, m97-style 128x128 tile)
template <typename OutT, int BM, int BN, int FA, int FB>
__global__ __launch_bounds__(256) void gemm_bt(const uint16_t* __restrict__ A,
                                               const uint16_t* __restrict__ BT,
                                               OutT* __restrict__ C, int M, int N, int K,
                                               float scale) {
  __shared__ __attribute__((aligned(16))) uint16_t As[BM * 64];
  __shared__ __attribute__((aligned(16))) uint16_t Bs[BN * 64];
  gemm_dev<OutT, BM, BN, FA, FB>(As, Bs, A, BT, C, M, N, K, scale, blockIdx.x);
}

// ---------------- flash attention, d_eff = 32, kv-split x2, 4 waves/block ----------
__global__ __launch_bounds__(256) void attn_k(const uint16_t* __restrict__ Qf,
                                              const uint16_t* __restrict__ XK,
                                              const uint16_t* __restrict__ VT,
                                              const float* __restrict__ mask,
                                              const uint32_t* __restrict__ flag,
                                              float* __restrict__ Pacc,
                                              float2* __restrict__ Pms) {
  __shared__ __attribute__((aligned(16))) uint16_t Ks[2][64 * 32];
  __shared__ __attribute__((aligned(16))) uint16_t Vs[2][32 * 64];
  const int tid = threadIdx.x;
  const int lane = tid & 63, w = tid >> 6;
  const int lo = lane & 15, g = lane >> 4;
  const int bid = blockIdx.x;
  const int lb = (bid & 7) * 256 + (bid >> 3); // XCD-chunked (2048 % 8 == 0, bijective)
  const int qt = lb & 31, h = (lb >> 5) & 15, b = (lb >> 9) & 1, half = lb >> 10;
  const int q0 = qt * 64 + w * 16;
  const int kvbase = half * 1024;
  const bool trivial = (*flag != 0u);
  const float LOG2E = 1.4426950408889634f;

  short8 qf = *(const short8*)(Qf + ((size_t)(b * 2048 + q0 + lo)) * 512 + h * 32 + g * 8);

  const int sK = w * 64 + lane;
  const int rK = sK >> 2;
  const int cKg = (sK & 3) ^ (rK & 3) ^ ((rK >> 2) & 3);
  const uint16_t* Ksrc = XK + ((size_t)(b * 2048 + kvbase + rK)) * 512 + h * 32 + cKg * 8;
  const int fV = sK >> 3, cV = ((sK & 7) - fV) & 7;
  const uint16_t* Vsrc = VT + ((size_t)(b * 512 + h * 32 + fV)) * 2048 + kvbase + cV * 8;

  const int swzL = (lo & 3) ^ ((lo >> 2) & 3);
  const int cK = (g ^ swzL) * 8;
#if !HAVE_MFMA16
  const int vA = (((g) + lo) & 7) * 8;
  const int vB = (((g + 4) + lo) & 7) * 8;
  const int srcA = lo + 16 * ((2 * g) & 3);
  const int srcB = lo + 16 * ((2 * g + 1) & 3);
#endif

  float m = -1e30f, sp = 0.f;
  floatx4 acc0 = {0.f, 0.f, 0.f, 0.f}, acc1 = {0.f, 0.f, 0.f, 0.f};
  const floatx4 zf = {0.f, 0.f, 0.f, 0.f};

  __builtin_amdgcn_global_load_lds((const AS1 uint32_t*)Ksrc,
                                   (AS3 uint32_t*)(&Ks[0][0] + w * 512), 16, 0, 0);
  __builtin_amdgcn_global_load_lds((const AS1 uint32_t*)Vsrc,
                                   (AS3 uint32_t*)(&Vs[0][0] + w * 512), 16, 0, 0);
  __syncthreads();

  int buf = 0;
  for (int t = 0; t < 16; ++t) {
    if (t < 15) {
      __builtin_amdgcn_global_load_lds((const AS1 uint32_t*)(Ksrc + (size_t)(t + 1) * 64 * 512),
                                       (AS3 uint32_t*)(&Ks[buf ^ 1][0] + w * 512), 16, 0, 0);
      __builtin_amdgcn_global_load_lds((const AS1 uint32_t*)(Vsrc + (size_t)(t + 1) * 64),
                                       (AS3 uint32_t*)(&Vs[buf ^ 1][0] + w * 512), 16, 0, 0);
    }
    const uint16_t* Kb = &Ks[buf][0];
    const uint16_t* Vb = &Vs[buf][0];
    const int k0 = kvbase + t * 64;

    short8 kf0 = *(const short8*)(Kb + (lo) * 32 + cK);
    short8 kf1 = *(const short8*)(Kb + (lo + 16) * 32 + cK);
    short8 kf2 = *(const short8*)(Kb + (lo + 32) * 32 + cK);
    short8 kf3 = *(const short8*)(Kb + (lo + 48) * 32 + cK);
    floatx4 s0 = __builtin_amdgcn_mfma_f32_16x16x32_bf16(kf0, qf, zf, 0, 0, 0);
    floatx4 s1 = __builtin_amdgcn_mfma_f32_16x16x32_bf16(kf1, qf, zf, 0, 0, 0);
    floatx4 s2 = __builtin_amdgcn_mfma_f32_16x16x32_bf16(kf2, qf, zf, 0, 0, 0);
    floatx4 s3 = __builtin_amdgcn_mfma_f32_16x16x32_bf16(kf3, qf, zf, 0, 0, 0);

    if (!trivial) {
      const float* mp = mask + (size_t)(q0 + lo) * 2048 + k0 + g * 4;
      float4 m0v = *(const float4*)(mp);
      float4 m1v = *(const float4*)(mp + 16);
      float4 m2v = *(const float4*)(mp + 32);
      float4 m3v = *(const float4*)(mp + 48);
      s0[0] -= (1.f / m0v.x - 1.f) * LOG2E; s0[1] -= (1.f / m0v.y - 1.f) * LOG2E;
      s0[2] -= (1.f / m0v.z - 1.f) * LOG2E; s0[3] -= (1.f / m0v.w - 1.f) * LOG2E;
      s1[0] -= (1.f / m1v.x - 1.f) * LOG2E; s1[1] -= (1.f / m1v.y - 1.f) * LOG2E;
      s1[2] -= (1.f / m1v.z - 1.f) * LOG2E; s1[3] -= (1.f / m1v.w - 1.f) * LOG2E;
      s2[0] -= (1.f / m2v.x - 1.f) * LOG2E; s2[1] -= (1.f / m2v.y - 1.f) * LOG2E;
      s2[2] -= (1.f / m2v.z - 1.f) * LOG2E; s2[3] -= (1.f / m2v.w - 1.f) * LOG2E;
      s3[0] -= (1.f / m3v.x - 1.f) * LOG2E; s3[1] -= (1.f / m3v.y - 1.f) * LOG2E;
      s3[2] -= (1.f / m3v.z - 1.f) * LOG2E; s3[3] -= (1.f / m3v.w - 1.f) * LOG2E;
    }

    float a0 = fmaxf(fmaxf(s0[0], s0[1]), fmaxf(s0[2], s0[3]));
    float a1 = fmaxf(fmaxf(s1[0], s1[1]), fmaxf(s1[2], s1[3]));
    float a2 = fmaxf(fmaxf(s2[0], s2[1]), fmaxf(s2[2], s2[3]));
    float a3 = fmaxf(fmaxf(s3[0], s3[1]), fmaxf(s3[2], s3[3]));
    float pmax = fmaxf(fmaxf(a0, a1), fmaxf(a2, a3));

    if (!__all(pmax - m <= 8.f)) {
      float tm = pmax;
      tm = fmaxf(tm, __shfl_xor(tm, 16));
      tm = fmaxf(tm, __shfl_xor(tm, 32));
      float mn = fmaxf(m, tm);
      float f = __builtin_amdgcn_exp2f(m - mn);
      sp *= f;
#pragma unroll
      for (int r = 0; r < 4; ++r) { acc0[r] *= f; acc1[r] *= f; }
      m = mn;
    }

    float p0[4], p1[4], p2[4], p3[4];
#pragma unroll
    for (int r = 0; r < 4; ++r) {
      p0[r] = __builtin_amdgcn_exp2f(s0[r] - m);
      p1[r] = __builtin_amdgcn_exp2f(s1[r] - m);
      p2[r] = __builtin_amdgcn_exp2f(s2[r] - m);
      p3[r] = __builtin_amdgcn_exp2f(s3[r] - m);
    }
    sp += ((p0[0] + p0[1]) + (p0[2] + p0[3])) + ((p1[0] + p1[1]) + (p1[2] + p1[3])) +
          ((p2[0] + p2[1]) + (p2[2] + p2[3])) + ((p3[0] + p3[1]) + (p3[2] + p3[3]));

#if HAVE_MFMA16
#pragma unroll
    for (int c = 0; c < 4; ++c) {
      const float* pc = (c == 0) ? p0 : (c == 1) ? p1 : (c == 2) ? p2 : p3;
      union { uint32_t u[2]; short4v v; } pk;
      pk.u[0] = cvtpk(pc[0], pc[1]);
      pk.u[1] = cvtpk(pc[2], pc[3]);
      const int kc = 2 * c + (g >> 1);
      const int pA = (kc + lo) & 7;
      const int pB = (kc + lo + 16) & 7;
      short4v va = *(const short4v*)(Vb + lo * 64 + pA * 8 + (g & 1) * 4);
      short4v vb = *(const short4v*)(Vb + (lo + 16) * 64 + pB * 8 + (g & 1) * 4);
      acc0 = __builtin_amdgcn_mfma_f32_16x16x16bf16_1k(va, pk.v, acc0, 0, 0, 0);
      acc1 = __builtin_amdgcn_mfma_f32_16x16x16bf16_1k(vb, pk.v, acc1, 0, 0, 0);
    }
#else
    uint32_t u0 = cvtpk(p0[0], p0[1]), u1 = cvtpk(p0[2], p0[3]);
    uint32_t u2 = cvtpk(p1[0], p1[1]), u3 = cvtpk(p1[2], p1[3]);
    uint32_t u4 = cvtpk(p2[0], p2[1]), u5 = cvtpk(p2[2], p2[3]);
    uint32_t u6 = cvtpk(p3[0], p3[1]), u7 = cvtpk(p3[2], p3[3]);
    union { uint32_t u[4]; short8 v; } pfa, pfb;
    {
      uint32_t x0 = (uint32_t)__shfl((int)u0, srcA), x2 = (uint32_t)__shfl((int)u2, srcA);
      uint32_t x1 = (uint32_t)__shfl((int)u1, srcA), x3 = (uint32_t)__shfl((int)u3, srcA);
      uint32_t y0 = (uint32_t)__shfl((int)u0, srcB), y2 = (uint32_t)__shfl((int)u2, srcB);
      uint32_t y1 = (uint32_t)__shfl((int)u1, srcB), y3 = (uint32_t)__shfl((int)u3, srcB);
      pfa.u[0] = (g < 2) ? x0 : x2;
      pfa.u[1] = (g < 2) ? x1 : x3;
      pfa.u[2] = (g < 2) ? y0 : y2;
      pfa.u[3] = (g < 2) ? y1 : y3;
    }
    {
      uint32_t x4 = (uint32_t)__shfl((int)u4, srcA), x6 = (uint32_t)__shfl((int)u6, srcA);
      uint32_t x5 = (uint32_t)__shfl((int)u5, srcA), x7 = (uint32_t)__shfl((int)u7, srcA);
      uint32_t y4 = (uint32_t)__shfl((int)u4, srcB), y6 = (uint32_t)__shfl((int)u6, srcB);
      uint32_t y5 = (uint32_t)__shfl((int)u5, srcB), y7 = (uint32_t)__shfl((int)u7, srcB);
      pfb.u[0] = (g < 2) ? x4 : x6;
      pfb.u[1] = (g < 2) ? x5 : x7;
      pfb.u[2] = (g < 2) ? y4 : y6;
      pfb.u[3] = (g < 2) ? y5 : y7;
    }
    short8 v0a = *(const short8*)(Vb + lo * 64 + vA);
    short8 v1a = *(const short8*)(Vb + (lo + 16) * 64 + vA);
    short8 v0b = *(const short8*)(Vb + lo * 64 + vB);
    short8 v1b = *(const short8*)(Vb + (lo + 16) * 64 + vB);
    acc0 = __builtin_amdgcn_mfma_f32_16x16x32_bf16(v0a, pfa.v, acc0, 0, 0, 0);
    acc1 = __builtin_amdgcn_mfma_f32_16x16x32_bf16(v1a, pfa.v, acc1, 0, 0, 0);
    acc0 = __builtin_amdgcn_mfma_f32_16x16x32_bf16(v0b, pfb.v, acc0, 0, 0, 0);
    acc1 = __builtin_amdgcn_mfma_f32_16x16x32_bf16(v1b, pfb.v, acc1, 0, 0, 0);
#endif

    __syncthreads();
    buf ^= 1;
  }
  float s = sp;
  s += __shfl_xor(s, 16);
  s += __shfl_xor(s, 32);

  const size_t qidx = ((size_t)((half * 2 + b) * 16 + h)) * 2048 + q0 + lo;
  float* pacc = Pacc + qidx * 32;
  *(floatx4*)(pacc + 4 * g) = acc0;
  *(floatx4*)(pacc + 16 + 4 * g) = acc1;
  if (g == 0) Pms[qidx] = make_float2(m, s);
}

// ---------------- combine kv-split halves -> O32 (bf16) ----------------
__global__ __launch_bounds__(256) void combine_k(const float* __restrict__ Pacc,
                                                 const float2* __restrict__ Pms,
                                                 uint16_t* __restrict__ O32) {
  const int t = blockIdx.x * 256 + threadIdx.x; // 524288 threads
  const int f4 = t & 7;
  const int qq = (t >> 3) & 2047;
  const int h = (t >> 14) & 15;
  const int b = t >> 18;
  const size_t qidx0 = ((size_t)((0 + b) * 16 + h)) * 2048 + qq;
  const size_t qidx1 = ((size_t)((2 + b) * 16 + h)) * 2048 + qq;
  float2 ms0 = Pms[qidx0], ms1 = Pms[qidx1];
  float M = fmaxf(ms0.x, ms1.x);
  float w0 = __builtin_amdgcn_exp2f(ms0.x - M);
  float w1 = __builtin_amdgcn_exp2f(ms1.x - M);
  float inv = 1.0f / (ms0.y * w0 + ms1.y * w1);
  w0 *= inv; w1 *= inv;
  float4 a0 = *(const float4*)(Pacc + qidx0 * 32 + f4 * 4);
  float4 a1 = *(const float4*)(Pacc + qidx1 * 32 + f4 * 4);
  union { uint16_t u[4]; uint64_t q; } o;
  o.u[0] = f2bf(a0.x * w0 + a1.x * w1);
  o.u[1] = f2bf(a0.y * w0 + a1.y * w1);
  o.u[2] = f2bf(a0.z * w0 + a1.z * w1);
  o.u[3] = f2bf(a0.w * w0 + a1.w * w1);
  *(uint64_t*)(O32 + ((size_t)(b * 2048 + qq)) * 512 + h * 32 + f4 * 4) = o.q;
}

// ---------------- launch ----------------
extern "C" void kernel_launch(void* const* d_in, const int* in_sizes, int n_in,
                              void* d_out, int out_size, void* d_ws, size_t ws_size,
                              hipStream_t stream) {
  const float* q    = (const float*)d_in[0];
  const float* kv   = (const float*)d_in[1];
  const float* mask = (const float*)d_in[2];
  const float* Wq   = (const float*)d_in[3];
  const float* Wk   = (const float*)d_in[4];
  const float* Wv   = (const float*)d_in[5];
  const float* Wo   = (const float*)d_in[6];

  char* ws = (char*)d_ws;
  uint16_t* qb    = (uint16_t*)(ws);                  // 16 MB
  uint16_t* kvb   = (uint16_t*)(ws + (16ull << 20));  // 16 MB
  uint16_t* Qf    = (uint16_t*)(ws + (32ull << 20));  // 4 MB
  uint16_t* XK    = (uint16_t*)(ws + (36ull << 20));  // 4 MB
  uint16_t* VT    = (uint16_t*)(ws + (40ull << 20));  // 8 MB
  uint16_t* O32   = (uint16_t*)(ws + (48ull << 20));  // 4 MB
  uint16_t* WqFT  = (uint16_t*)(ws + (52ull << 20));  // 2 MB
  uint16_t* WkvT  = (uint16_t*)(ws + (54ull << 20));  // 4 MB
  uint16_t* WoFT  = (uint16_t*)(ws + (58ull << 20));  // 2 MB
  uint32_t* flag  = (uint32_t*)(ws + (60ull << 20));
  float*    Pacc  = (float*)(ws);                     // 16 MB, overlaps qb (dead by attn)
  float2*   Pms   = (float2*)(ws + (16ull << 20));    // 1 MB, overlaps kvb (dead by attn)

  const float SCALE2 = 0.08838834764831845f * 1.4426950408889634f;

  hipMemsetAsync(flag, 1, 4, stream); // 0x01010101 != 0 -> "trivial" until proven otherwise
  prep_k<<<22528, 256, 0, stream>>>(q, kv, mask, Wq, Wk, Wv, Wo,
                                    qb, kvb, WqFT, WkvT, WoFT, flag);
  proj_k<<<768, 256, 0, stream>>>(qb, kvb, WqFT, WkvT, Qf, XK, VT, SCALE2);
  attn_k<<<2048, 256, 0, stream>>>(Qf, XK, VT, mask, flag, Pacc, Pms);
  combine_k<<<2048, 256, 0, stream>>>(Pacc, Pms, O32);
  gemm_bt<float, 128, 128, 4, 4><<<512, 256, 0, stream>>>(O32, WoFT, (float*)d_out,
                                                          4096, 2048, 512, 1.0f);
}

// Round 7
// 147.256 us; speedup vs baseline: 1.4934x; 1.0157x over previous
//
#include <hip/hip_runtime.h>
#include <hip/hip_bf16.h>
#include <stdint.h>

typedef short short8 __attribute__((ext_vector_type(8)));
typedef short short4v __attribute__((ext_vector_type(4)));
typedef float floatx4 __attribute__((ext_vector_type(4)));

#define AS1 __attribute__((address_space(1)))
#define AS3 __attribute__((address_space(3)))
#define DEV static __device__ __forceinline__

#if __has_builtin(__builtin_amdgcn_mfma_f32_16x16x16bf16_1k)
#define HAVE_MFMA16 1
#else
#define HAVE_MFMA16 0
#endif

DEV uint16_t f2bf(float x) {
  union { float f; uint32_t u; } v; v.f = x;
  return (uint16_t)((v.u + 0x7fffu + ((v.u >> 16) & 1u)) >> 16);
}

DEV uint32_t cvtpk(float a, float b) {
  uint32_t r;
  asm("v_cvt_pk_bf16_f32 %0, %1, %2" : "=v"(r) : "v"(a), "v"(b));
  return r;
}

// ---------------- merged prep kernel (block-range routed) ----------------

DEV void cvt_bf16_f(const float* __restrict__ src, uint16_t* __restrict__ dst, int bid) {
  int i = bid * 256 + threadIdx.x;
  float4 v = ((const float4*)src)[i];
  union { uint16_t u[4]; uint64_t q; } o;
  o.u[0] = f2bf(v.x); o.u[1] = f2bf(v.y); o.u[2] = f2bf(v.z); o.u[3] = f2bf(v.w);
  ((uint64_t*)dst)[i] = o.q;
}

DEV void mask_scan_f(const float* __restrict__ mask, uint32_t* __restrict__ f, int bid) {
  int i = bid * 256 + threadIdx.x;
  const float4* p = (const float4*)mask;
  float4 a = p[i * 2], b = p[i * 2 + 1];
  bool bad = (a.x != 1.f) | (a.y != 1.f) | (a.z != 1.f) | (a.w != 1.f) |
             (b.x != 1.f) | (b.y != 1.f) | (b.z != 1.f) | (b.w != 1.f);
  if (bad) *f = 0u;
}

DEV void fold_wq_f(float (*tile)[33], const float* __restrict__ Wq,
                   uint16_t* __restrict__ WqFT, int bid) {
  const int t = threadIdx.x;
  const int j0 = (bid / 64) * 32, k0 = (bid % 64) * 32;
  {
    const int tj = t & 31, tk8 = t >> 5;
    const int j = j0 + tj;
    const int base = 128 * (j >> 5) + 4 * (j & 31);
    for (int kk = 0; kk < 4; ++kk) {
      int kl = tk8 * 4 + kk;
      float4 w = *(const float4*)(Wq + (size_t)(k0 + kl) * 2048 + base);
      tile[tj][kl] = w.x + w.y + w.z + w.w;
    }
  }
  __syncthreads();
  {
    const int tk = t & 31, tj8 = t >> 5;
    for (int jj = 0; jj < 4; ++jj) {
      int jl = tj8 * 4 + jj;
      WqFT[(size_t)(j0 + jl) * 2048 + k0 + tk] = f2bf(tile[jl][tk]);
    }
  }
}

DEV void wkv_t_f(float (*tile)[33], const float* __restrict__ Wk,
                 const float* __restrict__ Wv, uint16_t* __restrict__ WkvT, int bid) {
  const int t = threadIdx.x;
  const int j0 = (bid / 64) * 32, k0 = (bid % 64) * 32;
  const float* src = (j0 < 512) ? Wk : Wv;
  const int jb = (j0 < 512) ? j0 : j0 - 512;
  {
    const int tj = t & 31, tk8 = t >> 5;
    for (int kk = 0; kk < 4; ++kk) {
      int kl = tk8 * 4 + kk;
      tile[tj][kl] = src[(size_t)(k0 + kl) * 512 + jb + tj];
    }
  }
  __syncthreads();
  {
    const int tk = t & 31, tj8 = t >> 5;
    for (int jj = 0; jj < 4; ++jj) {
      int jl = tj8 * 4 + jj;
      WkvT[(size_t)(j0 + jl) * 2048 + k0 + tk] = f2bf(tile[jl][tk]);
    }
  }
}

DEV void wof_t_f(float (*tile)[33], const float* __restrict__ Wo,
                 uint16_t* __restrict__ WoFT, int bid) {
  const int t = threadIdx.x;
  const int n0 = (bid / 16) * 32, j0 = (bid % 16) * 32;
  {
    const int tn = t & 31, tj8 = t >> 5;
    for (int jj = 0; jj < 4; ++jj) {
      int jl = tj8 * 4 + jj;
      int j = j0 + jl;
      int base = 128 * (j >> 5) + 4 * (j & 31);
      float ssum = 0.f;
      for (int r = 0; r < 4; ++r) ssum += Wo[(size_t)(base + r) * 2048 + n0 + tn];
      tile[tn][jl] = ssum;
    }
  }
  __syncthreads();
  {
    const int tj = t & 31, tn8 = t >> 5;
    for (int nn = 0; nn < 4; ++nn) {
      int nl = tn8 * 4 + nn;
      WoFT[(size_t)(n0 + nl) * 512 + j0 + tj] = f2bf(tile[nl][tj]);
    }
  }
}

__global__ __launch_bounds__(256) void prep_k(const float* __restrict__ q,
                                              const float* __restrict__ kv,
                                              const float* __restrict__ mask,
                                              const float* __restrict__ Wq,
                                              const float* __restrict__ Wk,
                                              const float* __restrict__ Wv,
                                              const float* __restrict__ Wo,
                                              uint16_t* __restrict__ qb,
                                              uint16_t* __restrict__ kvb,
                                              uint16_t* __restrict__ WqFT,
                                              uint16_t* __restrict__ WkvT,
                                              uint16_t* __restrict__ WoFT,
                                              uint32_t* __restrict__ flag) {
  __shared__ float tile[32][33];
  const int bid = blockIdx.x;
  if (bid < 8192)        cvt_bf16_f(q, qb, bid);
  else if (bid < 16384)  cvt_bf16_f(kv, kvb, bid - 8192);
  else if (bid < 18432)  mask_scan_f(mask, flag, bid - 16384);
  else if (bid < 19456)  fold_wq_f(tile, Wq, WqFT, bid - 18432);
  else if (bid < 21504)  wkv_t_f(tile, Wk, Wv, WkvT, bid - 19456);
  else                   wof_t_f(tile, Wo, WoFT, bid - 21504);
}

// ------- shared device GEMM tile: C[m0:+BM, n0:+BN] = A @ BT^T ----------
template <typename OutT, int BM, int BN, int FA, int FB>
DEV void gemm_dev(uint16_t* __restrict__ As, uint16_t* __restrict__ Bs,
                  const uint16_t* __restrict__ A, const uint16_t* __restrict__ BT,
                  OutT* __restrict__ C, int N, int K, float scale, int m0, int n0) {
  constexpr int BK = 64;
  const int lane = threadIdx.x & 63, wave = threadIdx.x >> 6;
  const int lo = lane & 15, g = lane >> 4;
  const int wm = wave >> 1, wn = wave & 1;
  constexpr int CA = BM / 32, CB = BN / 32;
  floatx4 acc[FA][FB] = {};

  for (int k0 = 0; k0 < K; k0 += BK) {
#pragma unroll
    for (int c = 0; c < CA; ++c) {
      int slot = (wave * CA + c) * 64 + lane;
      int row = slot >> 3, col = (slot & 7) * 8;
      __builtin_amdgcn_global_load_lds((const AS1 uint32_t*)(A + (size_t)(m0 + row) * K + k0 + col),
                                       (AS3 uint32_t*)(As + (size_t)(wave * CA + c) * 512), 16, 0, 0);
    }
#pragma unroll
    for (int c = 0; c < CB; ++c) {
      int slot = (wave * CB + c) * 64 + lane;
      int row = slot >> 3, col = (slot & 7) * 8;
      __builtin_amdgcn_global_load_lds((const AS1 uint32_t*)(BT + (size_t)(n0 + row) * K + k0 + col),
                                       (AS3 uint32_t*)(Bs + (size_t)(wave * CB + c) * 512), 16, 0, 0);
    }
    __syncthreads();
#pragma unroll
    for (int kk = 0; kk < BK; kk += 32) {
      short8 af[FA], bf[FB];
#pragma unroll
      for (int fa = 0; fa < FA; ++fa)
        af[fa] = *(const short8*)&As[(wm * FA * 16 + fa * 16 + lo) * BK + kk + g * 8];
#pragma unroll
      for (int fb = 0; fb < FB; ++fb)
        bf[fb] = *(const short8*)&Bs[(wn * FB * 16 + fb * 16 + lo) * BK + kk + g * 8];
#pragma unroll
      for (int fa = 0; fa < FA; ++fa)
#pragma unroll
        for (int fb = 0; fb < FB; ++fb)
          acc[fa][fb] = __builtin_amdgcn_mfma_f32_16x16x32_bf16(af[fa], bf[fb], acc[fa][fb], 0, 0, 0);
    }
    __syncthreads();
  }
#pragma unroll
  for (int fa = 0; fa < FA; ++fa)
#pragma unroll
    for (int fb = 0; fb < FB; ++fb)
#pragma unroll
      for (int r = 0; r < 4; ++r) {
        int row = m0 + wm * FA * 16 + fa * 16 + g * 4 + r;
        int col = n0 + wn * FB * 16 + fb * 16 + lo;
        if constexpr (sizeof(OutT) == 2)
          C[(size_t)row * N + col] = (OutT)f2bf(acc[fa][fb][r] * scale);
        else
          C[(size_t)row * N + col] = (OutT)(acc[fa][fb][r] * scale);
      }
}

// merged projections, 128x128 tiles, XCD-chunked (384 blocks, 48/XCD)
// sections: [0,128) Q (n-major), [128,256) K (n-major), [256,384) V (m-major, batched)
__global__ __launch_bounds__(256) void proj_k(const uint16_t* __restrict__ qb,
                                              const uint16_t* __restrict__ kvb,
                                              const uint16_t* __restrict__ WqFT,
                                              const uint16_t* __restrict__ WkvT,
                                              uint16_t* __restrict__ Qf,
                                              uint16_t* __restrict__ XK,
                                              uint16_t* __restrict__ VT,
                                              float scale2) {
  __shared__ __attribute__((aligned(16))) uint16_t As[128 * 64];
  __shared__ __attribute__((aligned(16))) uint16_t Bs[128 * 64];
  const int bid = blockIdx.x;
  const int lb = (bid & 7) * 48 + (bid >> 3); // 384 % 8 == 0, bijective
  if (lb < 128) {
    // Q-proj: [4096,512] = qb @ WqFT^T ; n-major tile order
    gemm_dev<uint16_t, 128, 128, 4, 4>(As, Bs, qb, WqFT, Qf, 512, 2048, scale2,
                                       (lb >> 2) * 128, (lb & 3) * 128);
  } else if (lb < 256) {
    const int t = lb - 128;
    gemm_dev<uint16_t, 128, 128, 4, 4>(As, Bs, kvb, WkvT, XK, 512, 2048, 1.0f,
                                       (t >> 2) * 128, (t & 3) * 128);
  } else {
    // V-proj (batched): VT[b] [512,2048] = W_V @ kvb[b]^T ; m-major tile order
    const int t = lb - 256;
    const int b = t >> 6, r = t & 63;
    gemm_dev<uint16_t, 128, 128, 4, 4>(As, Bs, WkvT + 512 * 2048,
                                       kvb + (size_t)b * 2048 * 2048,
                                       VT + (size_t)b * 512 * 2048,
                                       2048, 2048, 1.0f, (r & 3) * 128, (r >> 2) * 128);
  }
}

// O-projection: [4096,2048] fp32 = O32 @ WoFT^T, 128x128, XCD-chunked, n-major
__global__ __launch_bounds__(256) void oproj_k(const uint16_t* __restrict__ A,
                                               const uint16_t* __restrict__ BT,
                                               float* __restrict__ C) {
  __shared__ __attribute__((aligned(16))) uint16_t As[128 * 64];
  __shared__ __attribute__((aligned(16))) uint16_t Bs[128 * 64];
  const int lb = (blockIdx.x & 7) * 64 + (blockIdx.x >> 3); // 512 % 8 == 0
  gemm_dev<float, 128, 128, 4, 4>(As, Bs, A, BT, C, 2048, 512, 1.0f,
                                  (lb >> 4) * 128, (lb & 15) * 128);
}

// ---------------- flash attention, d_eff = 32, kv-split x2, 4 waves/block ----------
__global__ __launch_bounds__(256) void attn_k(const uint16_t* __restrict__ Qf,
                                              const uint16_t* __restrict__ XK,
                                              const uint16_t* __restrict__ VT,
                                              const float* __restrict__ mask,
                                              const uint32_t* __restrict__ flag,
                                              float* __restrict__ Pacc,
                                              float2* __restrict__ Pms) {
  __shared__ __attribute__((aligned(16))) uint16_t Ks[2][64 * 32];
  __shared__ __attribute__((aligned(16))) uint16_t Vs[2][32 * 64];
  const int tid = threadIdx.x;
  const int lane = tid & 63, w = tid >> 6;
  const int lo = lane & 15, g = lane >> 4;
  const int bid = blockIdx.x;
  const int lb = (bid & 7) * 256 + (bid >> 3); // XCD-chunked (2048 % 8 == 0, bijective)
  const int qt = lb & 31, h = (lb >> 5) & 15, b = (lb >> 9) & 1, half = lb >> 10;
  const int q0 = qt * 64 + w * 16;
  const int kvbase = half * 1024;
  const bool trivial = (*flag != 0u);
  const float LOG2E = 1.4426950408889634f;

  short8 qf = *(const short8*)(Qf + ((size_t)(b * 2048 + q0 + lo)) * 512 + h * 32 + g * 8);

  const int sK = w * 64 + lane;
  const int rK = sK >> 2;
  const int cKg = (sK & 3) ^ (rK & 3) ^ ((rK >> 2) & 3);
  const uint16_t* Ksrc = XK + ((size_t)(b * 2048 + kvbase + rK)) * 512 + h * 32 + cKg * 8;
  const int fV = sK >> 3, cV = ((sK & 7) - fV) & 7;
  const uint16_t* Vsrc = VT + ((size_t)(b * 512 + h * 32 + fV)) * 2048 + kvbase + cV * 8;

  const int swzL = (lo & 3) ^ ((lo >> 2) & 3);
  const int cK = (g ^ swzL) * 8;
#if !HAVE_MFMA16
  const int vA = (((g) + lo) & 7) * 8;
  const int vB = (((g + 4) + lo) & 7) * 8;
  const int srcA = lo + 16 * ((2 * g) & 3);
  const int srcB = lo + 16 * ((2 * g + 1) & 3);
#endif

  float m = -1e30f, sp = 0.f;
  floatx4 acc0 = {0.f, 0.f, 0.f, 0.f}, acc1 = {0.f, 0.f, 0.f, 0.f};
  const floatx4 zf = {0.f, 0.f, 0.f, 0.f};

  __builtin_amdgcn_global_load_lds((const AS1 uint32_t*)Ksrc,
                                   (AS3 uint32_t*)(&Ks[0][0] + w * 512), 16, 0, 0);
  __builtin_amdgcn_global_load_lds((const AS1 uint32_t*)Vsrc,
                                   (AS3 uint32_t*)(&Vs[0][0] + w * 512), 16, 0, 0);
  __syncthreads();

  int buf = 0;
  for (int t = 0; t < 16; ++t) {
    if (t < 15) {
      __builtin_amdgcn_global_load_lds((const AS1 uint32_t*)(Ksrc + (size_t)(t + 1) * 64 * 512),
                                       (AS3 uint32_t*)(&Ks[buf ^ 1][0] + w * 512), 16, 0, 0);
      __builtin_amdgcn_global_load_lds((const AS1 uint32_t*)(Vsrc + (size_t)(t + 1) * 64),
                                       (AS3 uint32_t*)(&Vs[buf ^ 1][0] + w * 512), 16, 0, 0);
    }
    const uint16_t* Kb = &Ks[buf][0];
    const uint16_t* Vb = &Vs[buf][0];
    const int k0 = kvbase + t * 64;

    short8 kf0 = *(const short8*)(Kb + (lo) * 32 + cK);
    short8 kf1 = *(const short8*)(Kb + (lo + 16) * 32 + cK);
    short8 kf2 = *(const short8*)(Kb + (lo + 32) * 32 + cK);
    short8 kf3 = *(const short8*)(Kb + (lo + 48) * 32 + cK);
    floatx4 s0 = __builtin_amdgcn_mfma_f32_16x16x32_bf16(kf0, qf, zf, 0, 0, 0);
    floatx4 s1 = __builtin_amdgcn_mfma_f32_16x16x32_bf16(kf1, qf, zf, 0, 0, 0);
    floatx4 s2 = __builtin_amdgcn_mfma_f32_16x16x32_bf16(kf2, qf, zf, 0, 0, 0);
    floatx4 s3 = __builtin_amdgcn_mfma_f32_16x16x32_bf16(kf3, qf, zf, 0, 0, 0);

    if (!trivial) {
      const float* mp = mask + (size_t)(q0 + lo) * 2048 + k0 + g * 4;
      float4 m0v = *(const float4*)(mp);
      float4 m1v = *(const float4*)(mp + 16);
      float4 m2v = *(const float4*)(mp + 32);
      float4 m3v = *(const float4*)(mp + 48);
      s0[0] -= (1.f / m0v.x - 1.f) * LOG2E; s0[1] -= (1.f / m0v.y - 1.f) * LOG2E;
      s0[2] -= (1.f / m0v.z - 1.f) * LOG2E; s0[3] -= (1.f / m0v.w - 1.f) * LOG2E;
      s1[0] -= (1.f / m1v.x - 1.f) * LOG2E; s1[1] -= (1.f / m1v.y - 1.f) * LOG2E;
      s1[2] -= (1.f / m1v.z - 1.f) * LOG2E; s1[3] -= (1.f / m1v.w - 1.f) * LOG2E;
      s2[0] -= (1.f / m2v.x - 1.f) * LOG2E; s2[1] -= (1.f / m2v.y - 1.f) * LOG2E;
      s2[2] -= (1.f / m2v.z - 1.f) * LOG2E; s2[3] -= (1.f / m2v.w - 1.f) * LOG2E;
      s3[0] -= (1.f / m3v.x - 1.f) * LOG2E; s3[1] -= (1.f / m3v.y - 1.f) * LOG2E;
      s3[2] -= (1.f / m3v.z - 1.f) * LOG2E; s3[3] -= (1.f / m3v.w - 1.f) * LOG2E;
    }

    float a0 = fmaxf(fmaxf(s0[0], s0[1]), fmaxf(s0[2], s0[3]));
    float a1 = fmaxf(fmaxf(s1[0], s1[1]), fmaxf(s1[2], s1[3]));
    float a2 = fmaxf(fmaxf(s2[0], s2[1]), fmaxf(s2[2], s2[3]));
    float a3 = fmaxf(fmaxf(s3[0], s3[1]), fmaxf(s3[2], s3[3]));
    float pmax = fmaxf(fmaxf(a0, a1), fmaxf(a2, a3));

    if (!__all(pmax - m <= 8.f)) {
      float tm = pmax;
      tm = fmaxf(tm, __shfl_xor(tm, 16));
      tm = fmaxf(tm, __shfl_xor(tm, 32));
      float mn = fmaxf(m, tm);
      float f = __builtin_amdgcn_exp2f(m - mn);
      sp *= f;
#pragma unroll
      for (int r = 0; r < 4; ++r) { acc0[r] *= f; acc1[r] *= f; }
      m = mn;
    }

    float p0[4], p1[4], p2[4], p3[4];
#pragma unroll
    for (int r = 0; r < 4; ++r) {
      p0[r] = __builtin_amdgcn_exp2f(s0[r] - m);
      p1[r] = __builtin_amdgcn_exp2f(s1[r] - m);
      p2[r] = __builtin_amdgcn_exp2f(s2[r] - m);
      p3[r] = __builtin_amdgcn_exp2f(s3[r] - m);
    }
    sp += ((p0[0] + p0[1]) + (p0[2] + p0[3])) + ((p1[0] + p1[1]) + (p1[2] + p1[3])) +
          ((p2[0] + p2[1]) + (p2[2] + p2[3])) + ((p3[0] + p3[1]) + (p3[2] + p3[3]));

#if HAVE_MFMA16
#pragma unroll
    for (int c = 0; c < 4; ++c) {
      const float* pc = (c == 0) ? p0 : (c == 1) ? p1 : (c == 2) ? p2 : p3;
      union { uint32_t u[2]; short4v v; } pk;
      pk.u[0] = cvtpk(pc[0], pc[1]);
      pk.u[1] = cvtpk(pc[2], pc[3]);
      const int kc = 2 * c + (g >> 1);
      const int pA = (kc + lo) & 7;
      const int pB = (kc + lo + 16) & 7;
      short4v va = *(const short4v*)(Vb + lo * 64 + pA * 8 + (g & 1) * 4);
      short4v vb = *(const short4v*)(Vb + (lo + 16) * 64 + pB * 8 + (g & 1) * 4);
      acc0 = __builtin_amdgcn_mfma_f32_16x16x16bf16_1k(va, pk.v, acc0, 0, 0, 0);
      acc1 = __builtin_amdgcn_mfma_f32_16x16x16bf16_1k(vb, pk.v, acc1, 0, 0, 0);
    }
#else
    uint32_t u0 = cvtpk(p0[0], p0[1]), u1 = cvtpk(p0[2], p0[3]);
    uint32_t u2 = cvtpk(p1[0], p1[1]), u3 = cvtpk(p1[2], p1[3]);
    uint32_t u4 = cvtpk(p2[0], p2[1]), u5 = cvtpk(p2[2], p2[3]);
    uint32_t u6 = cvtpk(p3[0], p3[1]), u7 = cvtpk(p3[2], p3[3]);
    union { uint32_t u[4]; short8 v; } pfa, pfb;
    {
      uint32_t x0 = (uint32_t)__shfl((int)u0, srcA), x2 = (uint32_t)__shfl((int)u2, srcA);
      uint32_t x1 = (uint32_t)__shfl((int)u1, srcA), x3 = (uint32_t)__shfl((int)u3, srcA);
      uint32_t y0 = (uint32_t)__shfl((int)u0, srcB), y2 = (uint32_t)__shfl((int)u2, srcB);
      uint32_t y1 = (uint32_t)__shfl((int)u1, srcB), y3 = (uint32_t)__shfl((int)u3, srcB);
      pfa.u[0] = (g < 2) ? x0 : x2;
      pfa.u[1] = (g < 2) ? x1 : x3;
      pfa.u[2] = (g < 2) ? y0 : y2;
      pfa.u[3] = (g < 2) ? y1 : y3;
    }
    {
      uint32_t x4 = (uint32_t)__shfl((int)u4, srcA), x6 = (uint32_t)__shfl((int)u6, srcA);
      uint32_t x5 = (uint32_t)__shfl((int)u5, srcA), x7 = (uint32_t)__shfl((int)u7, srcA);
      uint32_t y4 = (uint32_t)__shfl((int)u4, srcB), y6 = (uint32_t)__shfl((int)u6, srcB);
      uint32_t y5 = (uint32_t)__shfl((int)u5, srcB), y7 = (uint32_t)__shfl((int)u7, srcB);
      pfb.u[0] = (g < 2) ? x4 : x6;
      pfb.u[1] = (g < 2) ? x5 : x7;
      pfb.u[2] = (g < 2) ? y4 : y6;
      pfb.u[3] = (g < 2) ? y5 : y7;
    }
    short8 v0a = *(const short8*)(Vb + lo * 64 + vA);
    short8 v1a = *(const short8*)(Vb + (lo + 16) * 64 + vA);
    short8 v0b = *(const short8*)(Vb + lo * 64 + vB);
    short8 v1b = *(const short8*)(Vb + (lo + 16) * 64 + vB);
    acc0 = __builtin_amdgcn_mfma_f32_16x16x32_bf16(v0a, pfa.v, acc0, 0, 0, 0);
    acc1 = __builtin_amdgcn_mfma_f32_16x16x32_bf16(v1a, pfa.v, acc1, 0, 0, 0);
    acc0 = __builtin_amdgcn_mfma_f32_16x16x32_bf16(v0b, pfb.v, acc0, 0, 0, 0);
    acc1 = __builtin_amdgcn_mfma_f32_16x16x32_bf16(v1b, pfb.v, acc1, 0, 0, 0);
#endif

    __syncthreads();
    buf ^= 1;
  }
  float s = sp;
  s += __shfl_xor(s, 16);
  s += __shfl_xor(s, 32);

  const size_t qidx = ((size_t)((half * 2 + b) * 16 + h)) * 2048 + q0 + lo;
  float* pacc = Pacc + qidx * 32;
  *(floatx4*)(pacc + 4 * g) = acc0;
  *(floatx4*)(pacc + 16 + 4 * g) = acc1;
  if (g == 0) Pms[qidx] = make_float2(m, s);
}

// ---------------- combine kv-split halves -> O32 (bf16) ----------------
__global__ __launch_bounds__(256) void combine_k(const float* __restrict__ Pacc,
                                                 const float2* __restrict__ Pms,
                                                 uint16_t* __restrict__ O32) {
  const int t = blockIdx.x * 256 + threadIdx.x; // 524288 threads
  const int f4 = t & 7;
  const int qq = (t >> 3) & 2047;
  const int h = (t >> 14) & 15;
  const int b = t >> 18;
  const size_t qidx0 = ((size_t)((0 + b) * 16 + h)) * 2048 + qq;
  const size_t qidx1 = ((size_t)((2 + b) * 16 + h)) * 2048 + qq;
  float2 ms0 = Pms[qidx0], ms1 = Pms[qidx1];
  float M = fmaxf(ms0.x, ms1.x);
  float w0 = __builtin_amdgcn_exp2f(ms0.x - M);
  float w1 = __builtin_amdgcn_exp2f(ms1.x - M);
  float inv = 1.0f / (ms0.y * w0 + ms1.y * w1);
  w0 *= inv; w1 *= inv;
  float4 a0 = *(const float4*)(Pacc + qidx0 * 32 + f4 * 4);
  float4 a1 = *(const float4*)(Pacc + qidx1 * 32 + f4 * 4);
  union { uint16_t u[4]; uint64_t q; } o;
  o.u[0] = f2bf(a0.x * w0 + a1.x * w1);
  o.u[1] = f2bf(a0.y * w0 + a1.y * w1);
  o.u[2] = f2bf(a0.z * w0 + a1.z * w1);
  o.u[3] = f2bf(a0.w * w0 + a1.w * w1);
  *(uint64_t*)(O32 + ((size_t)(b * 2048 + qq)) * 512 + h * 32 + f4 * 4) = o.q;
}

// ---------------- launch ----------------
extern "C" void kernel_launch(void* const* d_in, const int* in_sizes, int n_in,
                              void* d_out, int out_size, void* d_ws, size_t ws_size,
                              hipStream_t stream) {
  const float* q    = (const float*)d_in[0];
  const float* kv   = (const float*)d_in[1];
  const float* mask = (const float*)d_in[2];
  const float* Wq   = (const float*)d_in[3];
  const float* Wk   = (const float*)d_in[4];
  const float* Wv   = (const float*)d_in[5];
  const float* Wo   = (const float*)d_in[6];

  char* ws = (char*)d_ws;
  uint16_t* qb    = (uint16_t*)(ws);                  // 16 MB
  uint16_t* kvb   = (uint16_t*)(ws + (16ull << 20));  // 16 MB
  uint16_t* Qf    = (uint16_t*)(ws + (32ull << 20));  // 4 MB
  uint16_t* XK    = (uint16_t*)(ws + (36ull << 20));  // 4 MB
  uint16_t* VT    = (uint16_t*)(ws + (40ull << 20));  // 8 MB
  uint16_t* O32   = (uint16_t*)(ws + (48ull << 20));  // 4 MB
  uint16_t* WqFT  = (uint16_t*)(ws + (52ull << 20));  // 2 MB
  uint16_t* WkvT  = (uint16_t*)(ws + (54ull << 20));  // 4 MB
  uint16_t* WoFT  = (uint16_t*)(ws + (58ull << 20));  // 2 MB
  uint32_t* flag  = (uint32_t*)(ws + (60ull << 20));
  float*    Pacc  = (float*)(ws);                     // 16 MB, overlaps qb (dead by attn)
  float2*   Pms   = (float2*)(ws + (16ull << 20));    // 1 MB, overlaps kvb (dead by attn)

  const float SCALE2 = 0.08838834764831845f * 1.4426950408889634f;

  hipMemsetAsync(flag, 1, 4, stream); // 0x01010101 != 0 -> "trivial" until proven otherwise
  prep_k<<<22528, 256, 0, stream>>>(q, kv, mask, Wq, Wk, Wv, Wo,
                                    qb, kvb, WqFT, WkvT, WoFT, flag);
  proj_k<<<384, 256, 0, stream>>>(qb, kvb, WqFT, WkvT, Qf, XK, VT, SCALE2);
  attn_k<<<2048, 256, 0, stream>>>(Qf, XK, VT, mask, flag, Pacc, Pms);
  combine_k<<<2048, 256, 0, stream>>>(Pacc, Pms, O32);
  oproj_k<<<512, 256, 0, stream>>>(O32, WoFT, (float*)d_out);
}

// Round 8
// 143.317 us; speedup vs baseline: 1.5344x; 1.0275x over previous
//
#include <hip/hip_runtime.h>
#include <hip/hip_bf16.h>
#include <stdint.h>

typedef short short8 __attribute__((ext_vector_type(8)));
typedef short short4v __attribute__((ext_vector_type(4)));
typedef float floatx4 __attribute__((ext_vector_type(4)));

#define AS1 __attribute__((address_space(1)))
#define AS3 __attribute__((address_space(3)))
#define DEV static __device__ __forceinline__

#if __has_builtin(__builtin_amdgcn_mfma_f32_16x16x16bf16_1k)
#define HAVE_MFMA16 1
#else
#define HAVE_MFMA16 0
#endif

DEV uint16_t f2bf(float x) {
  union { float f; uint32_t u; } v; v.f = x;
  return (uint16_t)((v.u + 0x7fffu + ((v.u >> 16) & 1u)) >> 16);
}

DEV uint32_t cvtpk(float a, float b) {
  uint32_t r;
  asm("v_cvt_pk_bf16_f32 %0, %1, %2" : "=v"(r) : "v"(a), "v"(b));
  return r;
}

// ---------------- merged prep kernel (block-range routed) ----------------

DEV void cvt_bf16_f(const float* __restrict__ src, uint16_t* __restrict__ dst, int bid) {
  int i = bid * 256 + threadIdx.x;
  float4 v = ((const float4*)src)[i];
  union { uint16_t u[4]; uint64_t q; } o;
  o.u[0] = f2bf(v.x); o.u[1] = f2bf(v.y); o.u[2] = f2bf(v.z); o.u[3] = f2bf(v.w);
  ((uint64_t*)dst)[i] = o.q;
}

DEV void mask_scan_f(const float* __restrict__ mask, uint32_t* __restrict__ f, int bid) {
  int i = bid * 256 + threadIdx.x;
  const float4* p = (const float4*)mask;
  float4 a = p[i * 2], b = p[i * 2 + 1];
  bool bad = (a.x != 1.f) | (a.y != 1.f) | (a.z != 1.f) | (a.w != 1.f) |
             (b.x != 1.f) | (b.y != 1.f) | (b.z != 1.f) | (b.w != 1.f);
  if (bad) *f = 0u;
}

DEV void fold_wq_f(float (*tile)[33], const float* __restrict__ Wq,
                   uint16_t* __restrict__ WqFT, int bid) {
  const int t = threadIdx.x;
  const int j0 = (bid / 64) * 32, k0 = (bid % 64) * 32;
  {
    const int tj = t & 31, tk8 = t >> 5;
    const int j = j0 + tj;
    const int base = 128 * (j >> 5) + 4 * (j & 31);
    for (int kk = 0; kk < 4; ++kk) {
      int kl = tk8 * 4 + kk;
      float4 w = *(const float4*)(Wq + (size_t)(k0 + kl) * 2048 + base);
      tile[tj][kl] = w.x + w.y + w.z + w.w;
    }
  }
  __syncthreads();
  {
    const int tk = t & 31, tj8 = t >> 5;
    for (int jj = 0; jj < 4; ++jj) {
      int jl = tj8 * 4 + jj;
      WqFT[(size_t)(j0 + jl) * 2048 + k0 + tk] = f2bf(tile[jl][tk]);
    }
  }
}

DEV void wkv_t_f(float (*tile)[33], const float* __restrict__ Wk,
                 const float* __restrict__ Wv, uint16_t* __restrict__ WkvT, int bid) {
  const int t = threadIdx.x;
  const int j0 = (bid / 64) * 32, k0 = (bid % 64) * 32;
  const float* src = (j0 < 512) ? Wk : Wv;
  const int jb = (j0 < 512) ? j0 : j0 - 512;
  {
    const int tj = t & 31, tk8 = t >> 5;
    for (int kk = 0; kk < 4; ++kk) {
      int kl = tk8 * 4 + kk;
      tile[tj][kl] = src[(size_t)(k0 + kl) * 512 + jb + tj];
    }
  }
  __syncthreads();
  {
    const int tk = t & 31, tj8 = t >> 5;
    for (int jj = 0; jj < 4; ++jj) {
      int jl = tj8 * 4 + jj;
      WkvT[(size_t)(j0 + jl) * 2048 + k0 + tk] = f2bf(tile[jl][tk]);
    }
  }
}

DEV void wof_t_f(float (*tile)[33], const float* __restrict__ Wo,
                 uint16_t* __restrict__ WoFT, int bid) {
  const int t = threadIdx.x;
  const int n0 = (bid / 16) * 32, j0 = (bid % 16) * 32;
  {
    const int tn = t & 31, tj8 = t >> 5;
    for (int jj = 0; jj < 4; ++jj) {
      int jl = tj8 * 4 + jj;
      int j = j0 + jl;
      int base = 128 * (j >> 5) + 4 * (j & 31);
      float ssum = 0.f;
      for (int r = 0; r < 4; ++r) ssum += Wo[(size_t)(base + r) * 2048 + n0 + tn];
      tile[tn][jl] = ssum;
    }
  }
  __syncthreads();
  {
    const int tj = t & 31, tn8 = t >> 5;
    for (int nn = 0; nn < 4; ++nn) {
      int nl = tn8 * 4 + nn;
      WoFT[(size_t)(n0 + nl) * 512 + j0 + tj] = f2bf(tile[nl][tj]);
    }
  }
}

__global__ __launch_bounds__(256) void prep_k(const float* __restrict__ q,
                                              const float* __restrict__ kv,
                                              const float* __restrict__ mask,
                                              const float* __restrict__ Wq,
                                              const float* __restrict__ Wk,
                                              const float* __restrict__ Wv,
                                              const float* __restrict__ Wo,
                                              uint16_t* __restrict__ qb,
                                              uint16_t* __restrict__ kvb,
                                              uint16_t* __restrict__ WqFT,
                                              uint16_t* __restrict__ WkvT,
                                              uint16_t* __restrict__ WoFT,
                                              uint32_t* __restrict__ flag) {
  __shared__ float tile[32][33];
  const int bid = blockIdx.x;
  if (bid < 8192)        cvt_bf16_f(q, qb, bid);
  else if (bid < 16384)  cvt_bf16_f(kv, kvb, bid - 8192);
  else if (bid < 18432)  mask_scan_f(mask, flag, bid - 16384);
  else if (bid < 19456)  fold_wq_f(tile, Wq, WqFT, bid - 18432);
  else if (bid < 21504)  wkv_t_f(tile, Wk, Wv, WkvT, bid - 19456);
  else                   wof_t_f(tile, Wo, WoFT, bid - 21504);
}

// ------- shared device GEMM tile: C[m0:+BM, n0:+BN] = A @ BT^T ----------
template <typename OutT, int BM, int BN, int FA, int FB>
DEV void gemm_dev(uint16_t* __restrict__ As, uint16_t* __restrict__ Bs,
                  const uint16_t* __restrict__ A, const uint16_t* __restrict__ BT,
                  OutT* __restrict__ C, int N, int K, float scale, int m0, int n0) {
  constexpr int BK = 64;
  const int lane = threadIdx.x & 63, wave = threadIdx.x >> 6;
  const int lo = lane & 15, g = lane >> 4;
  const int wm = wave >> 1, wn = wave & 1;
  constexpr int CA = BM / 32, CB = BN / 32;
  floatx4 acc[FA][FB] = {};

  for (int k0 = 0; k0 < K; k0 += BK) {
#pragma unroll
    for (int c = 0; c < CA; ++c) {
      int slot = (wave * CA + c) * 64 + lane;
      int row = slot >> 3, col = (slot & 7) * 8;
      __builtin_amdgcn_global_load_lds((const AS1 uint32_t*)(A + (size_t)(m0 + row) * K + k0 + col),
                                       (AS3 uint32_t*)(As + (size_t)(wave * CA + c) * 512), 16, 0, 0);
    }
#pragma unroll
    for (int c = 0; c < CB; ++c) {
      int slot = (wave * CB + c) * 64 + lane;
      int row = slot >> 3, col = (slot & 7) * 8;
      __builtin_amdgcn_global_load_lds((const AS1 uint32_t*)(BT + (size_t)(n0 + row) * K + k0 + col),
                                       (AS3 uint32_t*)(Bs + (size_t)(wave * CB + c) * 512), 16, 0, 0);
    }
    __syncthreads();
#pragma unroll
    for (int kk = 0; kk < BK; kk += 32) {
      short8 af[FA], bf[FB];
#pragma unroll
      for (int fa = 0; fa < FA; ++fa)
        af[fa] = *(const short8*)&As[(wm * FA * 16 + fa * 16 + lo) * BK + kk + g * 8];
#pragma unroll
      for (int fb = 0; fb < FB; ++fb)
        bf[fb] = *(const short8*)&Bs[(wn * FB * 16 + fb * 16 + lo) * BK + kk + g * 8];
#pragma unroll
      for (int fa = 0; fa < FA; ++fa)
#pragma unroll
        for (int fb = 0; fb < FB; ++fb)
          acc[fa][fb] = __builtin_amdgcn_mfma_f32_16x16x32_bf16(af[fa], bf[fb], acc[fa][fb], 0, 0, 0);
    }
    __syncthreads();
  }
#pragma unroll
  for (int fa = 0; fa < FA; ++fa)
#pragma unroll
    for (int fb = 0; fb < FB; ++fb)
#pragma unroll
      for (int r = 0; r < 4; ++r) {
        int row = m0 + wm * FA * 16 + fa * 16 + g * 4 + r;
        int col = n0 + wn * FB * 16 + fb * 16 + lo;
        if constexpr (sizeof(OutT) == 2)
          C[(size_t)row * N + col] = (OutT)f2bf(acc[fa][fb][r] * scale);
        else
          C[(size_t)row * N + col] = (OutT)(acc[fa][fb][r] * scale);
      }
}

// merged projections, 128x64 tiles, XCD-chunked (768 blocks = 3/CU, 96 tiles/XCD)
// sections: [0,256) Q (n-major), [256,512) K (n-major), [512,768) V (m-major, batched)
__global__ __launch_bounds__(256) void proj_k(const uint16_t* __restrict__ qb,
                                              const uint16_t* __restrict__ kvb,
                                              const uint16_t* __restrict__ WqFT,
                                              const uint16_t* __restrict__ WkvT,
                                              uint16_t* __restrict__ Qf,
                                              uint16_t* __restrict__ XK,
                                              uint16_t* __restrict__ VT,
                                              float scale2) {
  __shared__ __attribute__((aligned(16))) uint16_t As[128 * 64];
  __shared__ __attribute__((aligned(16))) uint16_t Bs[64 * 64];
  const int bid = blockIdx.x;
  const int lb = (bid & 7) * 96 + (bid >> 3); // 768 % 8 == 0, bijective
  if (lb < 256) {
    // Q-proj: [4096,512] = qb @ WqFT^T ; n-major (A-panel reuse dist 1, B 2MB L2-res)
    gemm_dev<uint16_t, 128, 64, 4, 2>(As, Bs, qb, WqFT, Qf, 512, 2048, scale2,
                                      (lb >> 3) * 128, (lb & 7) * 64);
  } else if (lb < 512) {
    const int t = lb - 256;
    gemm_dev<uint16_t, 128, 64, 4, 2>(As, Bs, kvb, WkvT, XK, 512, 2048, 1.0f,
                                      (t >> 3) * 128, (t & 7) * 64);
  } else {
    // V-proj (batched): VT[b] [512,2048] = W_V @ kvb[b]^T ; m-major (B-panel reuse, A L2-res)
    const int t = lb - 512;
    const int b = t >> 7, r = t & 127;
    gemm_dev<uint16_t, 128, 64, 4, 2>(As, Bs, WkvT + 512 * 2048,
                                      kvb + (size_t)b * 2048 * 2048,
                                      VT + (size_t)b * 512 * 2048,
                                      2048, 2048, 1.0f, (r & 3) * 128, (r >> 2) * 64);
  }
}

// O-projection: [4096,2048] fp32 = O32 @ WoFT^T, 128x64, 1024 blocks = 4/CU, n-major
__global__ __launch_bounds__(256) void oproj_k(const uint16_t* __restrict__ A,
                                               const uint16_t* __restrict__ BT,
                                               float* __restrict__ C) {
  __shared__ __attribute__((aligned(16))) uint16_t As[128 * 64];
  __shared__ __attribute__((aligned(16))) uint16_t Bs[64 * 64];
  const int lb = (blockIdx.x & 7) * 128 + (blockIdx.x >> 3); // 1024 % 8 == 0
  gemm_dev<float, 128, 64, 4, 2>(As, Bs, A, BT, C, 2048, 512, 1.0f,
                                 (lb >> 5) * 128, (lb & 31) * 64);
}

// ---------------- flash attention, d_eff = 32, kv-split x2, 4 waves/block ----------
__global__ __launch_bounds__(256) void attn_k(const uint16_t* __restrict__ Qf,
                                              const uint16_t* __restrict__ XK,
                                              const uint16_t* __restrict__ VT,
                                              const float* __restrict__ mask,
                                              const uint32_t* __restrict__ flag,
                                              float* __restrict__ Pacc,
                                              float2* __restrict__ Pms) {
  __shared__ __attribute__((aligned(16))) uint16_t Ks[2][64 * 32];
  __shared__ __attribute__((aligned(16))) uint16_t Vs[2][32 * 64];
  const int tid = threadIdx.x;
  const int lane = tid & 63, w = tid >> 6;
  const int lo = lane & 15, g = lane >> 4;
  const int bid = blockIdx.x;
  const int lb = (bid & 7) * 256 + (bid >> 3); // XCD-chunked (2048 % 8 == 0, bijective)
  const int qt = lb & 31, h = (lb >> 5) & 15, b = (lb >> 9) & 1, half = lb >> 10;
  const int q0 = qt * 64 + w * 16;
  const int kvbase = half * 1024;
  const bool trivial = (*flag != 0u);
  const float LOG2E = 1.4426950408889634f;

  short8 qf = *(const short8*)(Qf + ((size_t)(b * 2048 + q0 + lo)) * 512 + h * 32 + g * 8);

  const int sK = w * 64 + lane;
  const int rK = sK >> 2;
  const int cKg = (sK & 3) ^ (rK & 3) ^ ((rK >> 2) & 3);
  const uint16_t* Ksrc = XK + ((size_t)(b * 2048 + kvbase + rK)) * 512 + h * 32 + cKg * 8;
  const int fV = sK >> 3, cV = ((sK & 7) - fV) & 7;
  const uint16_t* Vsrc = VT + ((size_t)(b * 512 + h * 32 + fV)) * 2048 + kvbase + cV * 8;

  const int swzL = (lo & 3) ^ ((lo >> 2) & 3);
  const int cK = (g ^ swzL) * 8;
#if !HAVE_MFMA16
  const int vA = (((g) + lo) & 7) * 8;
  const int vB = (((g + 4) + lo) & 7) * 8;
  const int srcA = lo + 16 * ((2 * g) & 3);
  const int srcB = lo + 16 * ((2 * g + 1) & 3);
#endif

  float m = -1e30f, sp = 0.f;
  floatx4 acc0 = {0.f, 0.f, 0.f, 0.f}, acc1 = {0.f, 0.f, 0.f, 0.f};
  const floatx4 zf = {0.f, 0.f, 0.f, 0.f};

  __builtin_amdgcn_global_load_lds((const AS1 uint32_t*)Ksrc,
                                   (AS3 uint32_t*)(&Ks[0][0] + w * 512), 16, 0, 0);
  __builtin_amdgcn_global_load_lds((const AS1 uint32_t*)Vsrc,
                                   (AS3 uint32_t*)(&Vs[0][0] + w * 512), 16, 0, 0);
  __syncthreads();

  int buf = 0;
  for (int t = 0; t < 16; ++t) {
    if (t < 15) {
      __builtin_amdgcn_global_load_lds((const AS1 uint32_t*)(Ksrc + (size_t)(t + 1) * 64 * 512),
                                       (AS3 uint32_t*)(&Ks[buf ^ 1][0] + w * 512), 16, 0, 0);
      __builtin_amdgcn_global_load_lds((const AS1 uint32_t*)(Vsrc + (size_t)(t + 1) * 64),
                                       (AS3 uint32_t*)(&Vs[buf ^ 1][0] + w * 512), 16, 0, 0);
    }
    const uint16_t* Kb = &Ks[buf][0];
    const uint16_t* Vb = &Vs[buf][0];
    const int k0 = kvbase + t * 64;

    short8 kf0 = *(const short8*)(Kb + (lo) * 32 + cK);
    short8 kf1 = *(const short8*)(Kb + (lo + 16) * 32 + cK);
    short8 kf2 = *(const short8*)(Kb + (lo + 32) * 32 + cK);
    short8 kf3 = *(const short8*)(Kb + (lo + 48) * 32 + cK);
    floatx4 s0 = __builtin_amdgcn_mfma_f32_16x16x32_bf16(kf0, qf, zf, 0, 0, 0);
    floatx4 s1 = __builtin_amdgcn_mfma_f32_16x16x32_bf16(kf1, qf, zf, 0, 0, 0);
    floatx4 s2 = __builtin_amdgcn_mfma_f32_16x16x32_bf16(kf2, qf, zf, 0, 0, 0);
    floatx4 s3 = __builtin_amdgcn_mfma_f32_16x16x32_bf16(kf3, qf, zf, 0, 0, 0);

    if (!trivial) {
      const float* mp = mask + (size_t)(q0 + lo) * 2048 + k0 + g * 4;
      float4 m0v = *(const float4*)(mp);
      float4 m1v = *(const float4*)(mp + 16);
      float4 m2v = *(const float4*)(mp + 32);
      float4 m3v = *(const float4*)(mp + 48);
      s0[0] -= (1.f / m0v.x - 1.f) * LOG2E; s0[1] -= (1.f / m0v.y - 1.f) * LOG2E;
      s0[2] -= (1.f / m0v.z - 1.f) * LOG2E; s0[3] -= (1.f / m0v.w - 1.f) * LOG2E;
      s1[0] -= (1.f / m1v.x - 1.f) * LOG2E; s1[1] -= (1.f / m1v.y - 1.f) * LOG2E;
      s1[2] -= (1.f / m1v.z - 1.f) * LOG2E; s1[3] -= (1.f / m1v.w - 1.f) * LOG2E;
      s2[0] -= (1.f / m2v.x - 1.f) * LOG2E; s2[1] -= (1.f / m2v.y - 1.f) * LOG2E;
      s2[2] -= (1.f / m2v.z - 1.f) * LOG2E; s2[3] -= (1.f / m2v.w - 1.f) * LOG2E;
      s3[0] -= (1.f / m3v.x - 1.f) * LOG2E; s3[1] -= (1.f / m3v.y - 1.f) * LOG2E;
      s3[2] -= (1.f / m3v.z - 1.f) * LOG2E; s3[3] -= (1.f / m3v.w - 1.f) * LOG2E;
    }

    float a0 = fmaxf(fmaxf(s0[0], s0[1]), fmaxf(s0[2], s0[3]));
    float a1 = fmaxf(fmaxf(s1[0], s1[1]), fmaxf(s1[2], s1[3]));
    float a2 = fmaxf(fmaxf(s2[0], s2[1]), fmaxf(s2[2], s2[3]));
    float a3 = fmaxf(fmaxf(s3[0], s3[1]), fmaxf(s3[2], s3[3]));
    float pmax = fmaxf(fmaxf(a0, a1), fmaxf(a2, a3));

    if (!__all(pmax - m <= 8.f)) {
      float tm = pmax;
      tm = fmaxf(tm, __shfl_xor(tm, 16));
      tm = fmaxf(tm, __shfl_xor(tm, 32));
      float mn = fmaxf(m, tm);
      float f = __builtin_amdgcn_exp2f(m - mn);
      sp *= f;
#pragma unroll
      for (int r = 0; r < 4; ++r) { acc0[r] *= f; acc1[r] *= f; }
      m = mn;
    }

    float p0[4], p1[4], p2[4], p3[4];
#pragma unroll
    for (int r = 0; r < 4; ++r) {
      p0[r] = __builtin_amdgcn_exp2f(s0[r] - m);
      p1[r] = __builtin_amdgcn_exp2f(s1[r] - m);
      p2[r] = __builtin_amdgcn_exp2f(s2[r] - m);
      p3[r] = __builtin_amdgcn_exp2f(s3[r] - m);
    }
    sp += ((p0[0] + p0[1]) + (p0[2] + p0[3])) + ((p1[0] + p1[1]) + (p1[2] + p1[3])) +
          ((p2[0] + p2[1]) + (p2[2] + p2[3])) + ((p3[0] + p3[1]) + (p3[2] + p3[3]));

#if HAVE_MFMA16
#pragma unroll
    for (int c = 0; c < 4; ++c) {
      const float* pc = (c == 0) ? p0 : (c == 1) ? p1 : (c == 2) ? p2 : p3;
      union { uint32_t u[2]; short4v v; } pk;
      pk.u[0] = cvtpk(pc[0], pc[1]);
      pk.u[1] = cvtpk(pc[2], pc[3]);
      const int kc = 2 * c + (g >> 1);
      const int pA = (kc + lo) & 7;
      const int pB = (kc + lo + 16) & 7;
      short4v va = *(const short4v*)(Vb + lo * 64 + pA * 8 + (g & 1) * 4);
      short4v vb = *(const short4v*)(Vb + (lo + 16) * 64 + pB * 8 + (g & 1) * 4);
      acc0 = __builtin_amdgcn_mfma_f32_16x16x16bf16_1k(va, pk.v, acc0, 0, 0, 0);
      acc1 = __builtin_amdgcn_mfma_f32_16x16x16bf16_1k(vb, pk.v, acc1, 0, 0, 0);
    }
#else
    uint32_t u0 = cvtpk(p0[0], p0[1]), u1 = cvtpk(p0[2], p0[3]);
    uint32_t u2 = cvtpk(p1[0], p1[1]), u3 = cvtpk(p1[2], p1[3]);
    uint32_t u4 = cvtpk(p2[0], p2[1]), u5 = cvtpk(p2[2], p2[3]);
    uint32_t u6 = cvtpk(p3[0], p3[1]), u7 = cvtpk(p3[2], p3[3]);
    union { uint32_t u[4]; short8 v; } pfa, pfb;
    {
      uint32_t x0 = (uint32_t)__shfl((int)u0, srcA), x2 = (uint32_t)__shfl((int)u2, srcA);
      uint32_t x1 = (uint32_t)__shfl((int)u1, srcA), x3 = (uint32_t)__shfl((int)u3, srcA);
      uint32_t y0 = (uint32_t)__shfl((int)u0, srcB), y2 = (uint32_t)__shfl((int)u2, srcB);
      uint32_t y1 = (uint32_t)__shfl((int)u1, srcB), y3 = (uint32_t)__shfl((int)u3, srcB);
      pfa.u[0] = (g < 2) ? x0 : x2;
      pfa.u[1] = (g < 2) ? x1 : x3;
      pfa.u[2] = (g < 2) ? y0 : y2;
      pfa.u[3] = (g < 2) ? y1 : y3;
    }
    {
      uint32_t x4 = (uint32_t)__shfl((int)u4, srcA), x6 = (uint32_t)__shfl((int)u6, srcA);
      uint32_t x5 = (uint32_t)__shfl((int)u5, srcA), x7 = (uint32_t)__shfl((int)u7, srcA);
      uint32_t y4 = (uint32_t)__shfl((int)u4, srcB), y6 = (uint32_t)__shfl((int)u6, srcB);
      uint32_t y5 = (uint32_t)__shfl((int)u5, srcB), y7 = (uint32_t)__shfl((int)u7, srcB);
      pfb.u[0] = (g < 2) ? x4 : x6;
      pfb.u[1] = (g < 2) ? x5 : x7;
      pfb.u[2] = (g < 2) ? y4 : y6;
      pfb.u[3] = (g < 2) ? y5 : y7;
    }
    short8 v0a = *(const short8*)(Vb + lo * 64 + vA);
    short8 v1a = *(const short8*)(Vb + (lo + 16) * 64 + vA);
    short8 v0b = *(const short8*)(Vb + lo * 64 + vB);
    short8 v1b = *(const short8*)(Vb + (lo + 16) * 64 + vB);
    acc0 = __builtin_amdgcn_mfma_f32_16x16x32_bf16(v0a, pfa.v, acc0, 0, 0, 0);
    acc1 = __builtin_amdgcn_mfma_f32_16x16x32_bf16(v1a, pfa.v, acc1, 0, 0, 0);
    acc0 = __builtin_amdgcn_mfma_f32_16x16x32_bf16(v0b, pfb.v, acc0, 0, 0, 0);
    acc1 = __builtin_amdgcn_mfma_f32_16x16x32_bf16(v1b, pfb.v, acc1, 0, 0, 0);
#endif

    __syncthreads();
    buf ^= 1;
  }
  float s = sp;
  s += __shfl_xor(s, 16);
  s += __shfl_xor(s, 32);

  const size_t qidx = ((size_t)((half * 2 + b) * 16 + h)) * 2048 + q0 + lo;
  float* pacc = Pacc + qidx * 32;
  *(floatx4*)(pacc + 4 * g) = acc0;
  *(floatx4*)(pacc + 16 + 4 * g) = acc1;
  if (g == 0) Pms[qidx] = make_float2(m, s);
}

// ---------------- combine kv-split halves -> O32 (bf16) ----------------
__global__ __launch_bounds__(256) void combine_k(const float* __restrict__ Pacc,
                                                 const float2* __restrict__ Pms,
                                                 uint16_t* __restrict__ O32) {
  const int t = blockIdx.x * 256 + threadIdx.x; // 524288 threads
  const int f4 = t & 7;
  const int qq = (t >> 3) & 2047;
  const int h = (t >> 14) & 15;
  const int b = t >> 18;
  const size_t qidx0 = ((size_t)((0 + b) * 16 + h)) * 2048 + qq;
  const size_t qidx1 = ((size_t)((2 + b) * 16 + h)) * 2048 + qq;
  float2 ms0 = Pms[qidx0], ms1 = Pms[qidx1];
  float M = fmaxf(ms0.x, ms1.x);
  float w0 = __builtin_amdgcn_exp2f(ms0.x - M);
  float w1 = __builtin_amdgcn_exp2f(ms1.x - M);
  float inv = 1.0f / (ms0.y * w0 + ms1.y * w1);
  w0 *= inv; w1 *= inv;
  float4 a0 = *(const float4*)(Pacc + qidx0 * 32 + f4 * 4);
  float4 a1 = *(const float4*)(Pacc + qidx1 * 32 + f4 * 4);
  union { uint16_t u[4]; uint64_t q; } o;
  o.u[0] = f2bf(a0.x * w0 + a1.x * w1);
  o.u[1] = f2bf(a0.y * w0 + a1.y * w1);
  o.u[2] = f2bf(a0.z * w0 + a1.z * w1);
  o.u[3] = f2bf(a0.w * w0 + a1.w * w1);
  *(uint64_t*)(O32 + ((size_t)(b * 2048 + qq)) * 512 + h * 32 + f4 * 4) = o.q;
}

// ---------------- launch ----------------
extern "C" void kernel_launch(void* const* d_in, const int* in_sizes, int n_in,
                              void* d_out, int out_size, void* d_ws, size_t ws_size,
                              hipStream_t stream) {
  const float* q    = (const float*)d_in[0];
  const float* kv   = (const float*)d_in[1];
  const float* mask = (const float*)d_in[2];
  const float* Wq   = (const float*)d_in[3];
  const float* Wk   = (const float*)d_in[4];
  const float* Wv   = (const float*)d_in[5];
  const float* Wo   = (const float*)d_in[6];

  char* ws = (char*)d_ws;
  uint16_t* qb    = (uint16_t*)(ws);                  // 16 MB
  uint16_t* kvb   = (uint16_t*)(ws + (16ull << 20));  // 16 MB
  uint16_t* Qf    = (uint16_t*)(ws + (32ull << 20));  // 4 MB
  uint16_t* XK    = (uint16_t*)(ws + (36ull << 20));  // 4 MB
  uint16_t* VT    = (uint16_t*)(ws + (40ull << 20));  // 8 MB
  uint16_t* O32   = (uint16_t*)(ws + (48ull << 20));  // 4 MB
  uint16_t* WqFT  = (uint16_t*)(ws + (52ull << 20));  // 2 MB
  uint16_t* WkvT  = (uint16_t*)(ws + (54ull << 20));  // 4 MB
  uint16_t* WoFT  = (uint16_t*)(ws + (58ull << 20));  // 2 MB
  uint32_t* flag  = (uint32_t*)(ws + (60ull << 20));
  float*    Pacc  = (float*)(ws);                     // 16 MB, overlaps qb (dead by attn)
  float2*   Pms   = (float2*)(ws + (16ull << 20));    // 1 MB, overlaps kvb (dead by attn)

  const float SCALE2 = 0.08838834764831845f * 1.4426950408889634f;

  hipMemsetAsync(flag, 1, 4, stream); // 0x01010101 != 0 -> "trivial" until proven otherwise
  prep_k<<<22528, 256, 0, stream>>>(q, kv, mask, Wq, Wk, Wv, Wo,
                                    qb, kvb, WqFT, WkvT, WoFT, flag);
  proj_k<<<768, 256, 0, stream>>>(qb, kvb, WqFT, WkvT, Qf, XK, VT, SCALE2);
  attn_k<<<2048, 256, 0, stream>>>(Qf, XK, VT, mask, flag, Pacc, Pms);
  combine_k<<<2048, 256, 0, stream>>>(Pacc, Pms, O32);
  oproj_k<<<1024, 256, 0, stream>>>(O32, WoFT, (float*)d_out);
}

// Round 11
// 141.360 us; speedup vs baseline: 1.5557x; 1.0138x over previous
//
#include <hip/hip_runtime.h>
#include <hip/hip_bf16.h>
#include <stdint.h>

typedef short short8 __attribute__((ext_vector_type(8)));
typedef short short4v __attribute__((ext_vector_type(4)));
typedef float floatx4 __attribute__((ext_vector_type(4)));

#define AS1 __attribute__((address_space(1)))
#define AS3 __attribute__((address_space(3)))
#define DEV static __device__ __forceinline__

#if __has_builtin(__builtin_amdgcn_mfma_f32_16x16x16bf16_1k)
#define HAVE_MFMA16 1
#else
#define HAVE_MFMA16 0
#endif

DEV uint16_t f2bf(float x) {
  union { float f; uint32_t u; } v; v.f = x;
  return (uint16_t)((v.u + 0x7fffu + ((v.u >> 16) & 1u)) >> 16);
}

DEV uint32_t cvtpk(float a, float b) {
  uint32_t r;
  asm("v_cvt_pk_bf16_f32 %0, %1, %2" : "=v"(r) : "v"(a), "v"(b));
  return r;
}

// ---------------- merged prep kernel (block-range routed) ----------------

DEV void cvt_bf16_f(const float* __restrict__ src, uint16_t* __restrict__ dst, int bid) {
  int i = bid * 256 + threadIdx.x;
  float4 v = ((const float4*)src)[i];
  union { uint16_t u[4]; uint64_t q; } o;
  o.u[0] = f2bf(v.x); o.u[1] = f2bf(v.y); o.u[2] = f2bf(v.z); o.u[3] = f2bf(v.w);
  ((uint64_t*)dst)[i] = o.q;
}

DEV void mask_scan_f(const float* __restrict__ mask, uint32_t* __restrict__ f, int bid) {
  int i = bid * 256 + threadIdx.x;
  const float4* p = (const float4*)mask;
  float4 a = p[i * 2], b = p[i * 2 + 1];
  bool bad = (a.x != 1.f) | (a.y != 1.f) | (a.z != 1.f) | (a.w != 1.f) |
             (b.x != 1.f) | (b.y != 1.f) | (b.z != 1.f) | (b.w != 1.f);
  if (bad) *f = 0u;
}

DEV void fold_wq_f(float (*tile)[33], const float* __restrict__ Wq,
                   uint16_t* __restrict__ WqFT, int bid) {
  const int t = threadIdx.x;
  const int j0 = (bid / 64) * 32, k0 = (bid % 64) * 32;
  {
    const int tj = t & 31, tk8 = t >> 5;
    const int j = j0 + tj;
    const int base = 128 * (j >> 5) + 4 * (j & 31);
    for (int kk = 0; kk < 4; ++kk) {
      int kl = tk8 * 4 + kk;
      float4 w = *(const float4*)(Wq + (size_t)(k0 + kl) * 2048 + base);
      tile[tj][kl] = w.x + w.y + w.z + w.w;
    }
  }
  __syncthreads();
  {
    const int tk = t & 31, tj8 = t >> 5;
    for (int jj = 0; jj < 4; ++jj) {
      int jl = tj8 * 4 + jj;
      WqFT[(size_t)(j0 + jl) * 2048 + k0 + tk] = f2bf(tile[jl][tk]);
    }
  }
}

DEV void wkv_t_f(float (*tile)[33], const float* __restrict__ Wk,
                 const float* __restrict__ Wv, uint16_t* __restrict__ WkvT, int bid) {
  const int t = threadIdx.x;
  const int j0 = (bid / 64) * 32, k0 = (bid % 64) * 32;
  const float* src = (j0 < 512) ? Wk : Wv;
  const int jb = (j0 < 512) ? j0 : j0 - 512;
  {
    const int tj = t & 31, tk8 = t >> 5;
    for (int kk = 0; kk < 4; ++kk) {
      int kl = tk8 * 4 + kk;
      tile[tj][kl] = src[(size_t)(k0 + kl) * 512 + jb + tj];
    }
  }
  __syncthreads();
  {
    const int tk = t & 31, tj8 = t >> 5;
    for (int jj = 0; jj < 4; ++jj) {
      int jl = tj8 * 4 + jj;
      WkvT[(size_t)(j0 + jl) * 2048 + k0 + tk] = f2bf(tile[jl][tk]);
    }
  }
}

DEV void wof_t_f(float (*tile)[33], const float* __restrict__ Wo,
                 uint16_t* __restrict__ WoFT, int bid) {
  const int t = threadIdx.x;
  const int n0 = (bid / 16) * 32, j0 = (bid % 16) * 32;
  {
    const int tn = t & 31, tj8 = t >> 5;
    for (int jj = 0; jj < 4; ++jj) {
      int jl = tj8 * 4 + jj;
      int j = j0 + jl;
      int base = 128 * (j >> 5) + 4 * (j & 31);
      float ssum = 0.f;
      for (int r = 0; r < 4; ++r) ssum += Wo[(size_t)(base + r) * 2048 + n0 + tn];
      tile[tn][jl] = ssum;
    }
  }
  __syncthreads();
  {
    const int tj = t & 31, tn8 = t >> 5;
    for (int nn = 0; nn < 4; ++nn) {
      int nl = tn8 * 4 + nn;
      WoFT[(size_t)(n0 + nl) * 512 + j0 + tj] = f2bf(tile[nl][tj]);
    }
  }
}

__global__ __launch_bounds__(256) void prep_k(const float* __restrict__ q,
                                              const float* __restrict__ kv,
                                              const float* __restrict__ mask,
                                              const float* __restrict__ Wq,
                                              const float* __restrict__ Wk,
                                              const float* __restrict__ Wv,
                                              const float* __restrict__ Wo,
                                              uint16_t* __restrict__ qb,
                                              uint16_t* __restrict__ kvb,
                                              uint16_t* __restrict__ WqFT,
                                              uint16_t* __restrict__ WkvT,
                                              uint16_t* __restrict__ WoFT,
                                              uint32_t* __restrict__ flag) {
  __shared__ float tile[32][33];
  const int bid = blockIdx.x;
  if (bid < 8192)        cvt_bf16_f(q, qb, bid);
  else if (bid < 16384)  cvt_bf16_f(kv, kvb, bid - 8192);
  else if (bid < 18432)  mask_scan_f(mask, flag, bid - 16384);
  else if (bid < 19456)  fold_wq_f(tile, Wq, WqFT, bid - 18432);
  else if (bid < 21504)  wkv_t_f(tile, Wk, Wv, WkvT, bid - 19456);
  else                   wof_t_f(tile, Wo, WoFT, bid - 21504);
}

// ------- shared device GEMM tile: C[m0:+BM, n0:+BN] = A @ BT^T ----------
template <typename OutT, int BM, int BN, int FA, int FB>
DEV void gemm_dev(uint16_t* __restrict__ As, uint16_t* __restrict__ Bs,
                  const uint16_t* __restrict__ A, const uint16_t* __restrict__ BT,
                  OutT* __restrict__ C, int N, int K, float scale, int m0, int n0) {
  constexpr int BK = 64;
  const int lane = threadIdx.x & 63, wave = threadIdx.x >> 6;
  const int lo = lane & 15, g = lane >> 4;
  const int wm = wave >> 1, wn = wave & 1;
  constexpr int CA = BM / 32, CB = BN / 32;
  floatx4 acc[FA][FB] = {};

  for (int k0 = 0; k0 < K; k0 += BK) {
#pragma unroll
    for (int c = 0; c < CA; ++c) {
      int slot = (wave * CA + c) * 64 + lane;
      int row = slot >> 3, col = (slot & 7) * 8;
      __builtin_amdgcn_global_load_lds((const AS1 uint32_t*)(A + (size_t)(m0 + row) * K + k0 + col),
                                       (AS3 uint32_t*)(As + (size_t)(wave * CA + c) * 512), 16, 0, 0);
    }
#pragma unroll
    for (int c = 0; c < CB; ++c) {
      int slot = (wave * CB + c) * 64 + lane;
      int row = slot >> 3, col = (slot & 7) * 8;
      __builtin_amdgcn_global_load_lds((const AS1 uint32_t*)(BT + (size_t)(n0 + row) * K + k0 + col),
                                       (AS3 uint32_t*)(Bs + (size_t)(wave * CB + c) * 512), 16, 0, 0);
    }
    __syncthreads();
#pragma unroll
    for (int kk = 0; kk < BK; kk += 32) {
      short8 af[FA], bf[FB];
#pragma unroll
      for (int fa = 0; fa < FA; ++fa)
        af[fa] = *(const short8*)&As[(wm * FA * 16 + fa * 16 + lo) * BK + kk + g * 8];
#pragma unroll
      for (int fb = 0; fb < FB; ++fb)
        bf[fb] = *(const short8*)&Bs[(wn * FB * 16 + fb * 16 + lo) * BK + kk + g * 8];
#pragma unroll
      for (int fa = 0; fa < FA; ++fa)
#pragma unroll
        for (int fb = 0; fb < FB; ++fb)
          acc[fa][fb] = __builtin_amdgcn_mfma_f32_16x16x32_bf16(af[fa], bf[fb], acc[fa][fb], 0, 0, 0);
    }
    __syncthreads();
  }
#pragma unroll
  for (int fa = 0; fa < FA; ++fa)
#pragma unroll
    for (int fb = 0; fb < FB; ++fb)
#pragma unroll
      for (int r = 0; r < 4; ++r) {
        int row = m0 + wm * FA * 16 + fa * 16 + g * 4 + r;
        int col = n0 + wn * FB * 16 + fb * 16 + lo;
        if constexpr (sizeof(OutT) == 2)
          C[(size_t)row * N + col] = (OutT)f2bf(acc[fa][fb][r] * scale);
        else
          C[(size_t)row * N + col] = (OutT)(acc[fa][fb][r] * scale);
      }
}

// merged projections, 128x64 tiles, XCD-chunked (768 blocks = 3/CU, 96 tiles/XCD)
__global__ __launch_bounds__(256) void proj_k(const uint16_t* __restrict__ qb,
                                              const uint16_t* __restrict__ kvb,
                                              const uint16_t* __restrict__ WqFT,
                                              const uint16_t* __restrict__ WkvT,
                                              uint16_t* __restrict__ Qf,
                                              uint16_t* __restrict__ XK,
                                              uint16_t* __restrict__ VT,
                                              float scale2) {
  __shared__ __attribute__((aligned(16))) uint16_t As[128 * 64];
  __shared__ __attribute__((aligned(16))) uint16_t Bs[64 * 64];
  const int bid = blockIdx.x;
  const int lb = (bid & 7) * 96 + (bid >> 3); // 768 % 8 == 0, bijective
  if (lb < 256) {
    gemm_dev<uint16_t, 128, 64, 4, 2>(As, Bs, qb, WqFT, Qf, 512, 2048, scale2,
                                      (lb >> 3) * 128, (lb & 7) * 64);
  } else if (lb < 512) {
    const int t = lb - 256;
    gemm_dev<uint16_t, 128, 64, 4, 2>(As, Bs, kvb, WkvT, XK, 512, 2048, 1.0f,
                                      (t >> 3) * 128, (t & 7) * 64);
  } else {
    const int t = lb - 512;
    const int b = t >> 7, r = t & 127;
    gemm_dev<uint16_t, 128, 64, 4, 2>(As, Bs, WkvT + 512 * 2048,
                                      kvb + (size_t)b * 2048 * 2048,
                                      VT + (size_t)b * 512 * 2048,
                                      2048, 2048, 1.0f, (r & 3) * 128, (r >> 2) * 64);
  }
}

// O-projection: [4096,2048] fp32 = O32 @ WoFT^T, 128x64, 1024 blocks = 4/CU, n-major
__global__ __launch_bounds__(256) void oproj_k(const uint16_t* __restrict__ A,
                                               const uint16_t* __restrict__ BT,
                                               float* __restrict__ C) {
  __shared__ __attribute__((aligned(16))) uint16_t As[128 * 64];
  __shared__ __attribute__((aligned(16))) uint16_t Bs[64 * 64];
  const int lb = (blockIdx.x & 7) * 128 + (blockIdx.x >> 3); // 1024 % 8 == 0
  gemm_dev<float, 128, 64, 4, 2>(As, Bs, A, BT, C, 2048, 512, 1.0f,
                                 (lb >> 5) * 128, (lb & 31) * 64);
}

// ---------------- flash attention, d_eff = 32, kv-split x2, 4 waves/block ----------
// Exact R8 structure/semantics. Only changes: balanced max tree (value-identical)
// and an explicit vmcnt(0) drain before the barrier (race hardening).
__global__ __launch_bounds__(256) void attn_k(const uint16_t* __restrict__ Qf,
                                              const uint16_t* __restrict__ XK,
                                              const uint16_t* __restrict__ VT,
                                              const float* __restrict__ mask,
                                              const uint32_t* __restrict__ flag,
                                              float* __restrict__ Pacc,
                                              float2* __restrict__ Pms) {
  __shared__ __attribute__((aligned(16))) uint16_t Ks[2][64 * 32];
  __shared__ __attribute__((aligned(16))) uint16_t Vs[2][32 * 64];
  const int tid = threadIdx.x;
  const int lane = tid & 63, w = tid >> 6;
  const int lo = lane & 15, g = lane >> 4;
  const int bid = blockIdx.x;
  const int lb = (bid & 7) * 256 + (bid >> 3); // XCD-chunked (2048 % 8 == 0, bijective)
  const int qt = lb & 31, h = (lb >> 5) & 15, b = (lb >> 9) & 1, half = lb >> 10;
  const int q0 = qt * 64 + w * 16;
  const int kvbase = half * 1024;
  const bool trivial = (*flag != 0u);
  const float LOG2E = 1.4426950408889634f;

  short8 qf = *(const short8*)(Qf + ((size_t)(b * 2048 + q0 + lo)) * 512 + h * 32 + g * 8);

  const int sK = w * 64 + lane;
  const int rK = sK >> 2;
  const int cKg = (sK & 3) ^ (rK & 3) ^ ((rK >> 2) & 3);
  const uint16_t* Ksrc = XK + ((size_t)(b * 2048 + kvbase + rK)) * 512 + h * 32 + cKg * 8;
  const int fV = sK >> 3, cV = ((sK & 7) - fV) & 7;
  const uint16_t* Vsrc = VT + ((size_t)(b * 512 + h * 32 + fV)) * 2048 + kvbase + cV * 8;

  const int swzL = (lo & 3) ^ ((lo >> 2) & 3);
  const int cK = (g ^ swzL) * 8;
#if !HAVE_MFMA16
  const int vA = (((g) + lo) & 7) * 8;
  const int vB = (((g + 4) + lo) & 7) * 8;
  const int srcA = lo + 16 * ((2 * g) & 3);
  const int srcB = lo + 16 * ((2 * g + 1) & 3);
#endif

  float m = -1e30f, sp = 0.f;
  floatx4 acc0 = {0.f, 0.f, 0.f, 0.f}, acc1 = {0.f, 0.f, 0.f, 0.f};
  const floatx4 zf = {0.f, 0.f, 0.f, 0.f};

  __builtin_amdgcn_global_load_lds((const AS1 uint32_t*)Ksrc,
                                   (AS3 uint32_t*)(&Ks[0][0] + w * 512), 16, 0, 0);
  __builtin_amdgcn_global_load_lds((const AS1 uint32_t*)Vsrc,
                                   (AS3 uint32_t*)(&Vs[0][0] + w * 512), 16, 0, 0);
  asm volatile("s_waitcnt vmcnt(0)" ::: "memory");
  __syncthreads();

  int buf = 0;
  for (int t = 0; t < 16; ++t) {
    if (t < 15) {
      __builtin_amdgcn_global_load_lds((const AS1 uint32_t*)(Ksrc + (size_t)(t + 1) * 64 * 512),
                                       (AS3 uint32_t*)(&Ks[buf ^ 1][0] + w * 512), 16, 0, 0);
      __builtin_amdgcn_global_load_lds((const AS1 uint32_t*)(Vsrc + (size_t)(t + 1) * 64),
                                       (AS3 uint32_t*)(&Vs[buf ^ 1][0] + w * 512), 16, 0, 0);
    }
    const uint16_t* Kb = &Ks[buf][0];
    const uint16_t* Vb = &Vs[buf][0];
    const int k0 = kvbase + t * 64;

    short8 kf0 = *(const short8*)(Kb + (lo) * 32 + cK);
    short8 kf1 = *(const short8*)(Kb + (lo + 16) * 32 + cK);
    short8 kf2 = *(const short8*)(Kb + (lo + 32) * 32 + cK);
    short8 kf3 = *(const short8*)(Kb + (lo + 48) * 32 + cK);
    floatx4 s0 = __builtin_amdgcn_mfma_f32_16x16x32_bf16(kf0, qf, zf, 0, 0, 0);
    floatx4 s1 = __builtin_amdgcn_mfma_f32_16x16x32_bf16(kf1, qf, zf, 0, 0, 0);
    floatx4 s2 = __builtin_amdgcn_mfma_f32_16x16x32_bf16(kf2, qf, zf, 0, 0, 0);
    floatx4 s3 = __builtin_amdgcn_mfma_f32_16x16x32_bf16(kf3, qf, zf, 0, 0, 0);

    if (!trivial) {
      const float* mp = mask + (size_t)(q0 + lo) * 2048 + k0 + g * 4;
      float4 m0v = *(const float4*)(mp);
      float4 m1v = *(const float4*)(mp + 16);
      float4 m2v = *(const float4*)(mp + 32);
      float4 m3v = *(const float4*)(mp + 48);
      s0[0] -= (1.f / m0v.x - 1.f) * LOG2E; s0[1] -= (1.f / m0v.y - 1.f) * LOG2E;
      s0[2] -= (1.f / m0v.z - 1.f) * LOG2E; s0[3] -= (1.f / m0v.w - 1.f) * LOG2E;
      s1[0] -= (1.f / m1v.x - 1.f) * LOG2E; s1[1] -= (1.f / m1v.y - 1.f) * LOG2E;
      s1[2] -= (1.f / m1v.z - 1.f) * LOG2E; s1[3] -= (1.f / m1v.w - 1.f) * LOG2E;
      s2[0] -= (1.f / m2v.x - 1.f) * LOG2E; s2[1] -= (1.f / m2v.y - 1.f) * LOG2E;
      s2[2] -= (1.f / m2v.z - 1.f) * LOG2E; s2[3] -= (1.f / m2v.w - 1.f) * LOG2E;
      s3[0] -= (1.f / m3v.x - 1.f) * LOG2E; s3[1] -= (1.f / m3v.y - 1.f) * LOG2E;
      s3[2] -= (1.f / m3v.z - 1.f) * LOG2E; s3[3] -= (1.f / m3v.w - 1.f) * LOG2E;
    }

    // balanced max tree over the same 16 values (depth 4, value-identical)
    float t0 = fmaxf(fmaxf(s0[0], s0[1]), s0[2]);
    float t1 = fmaxf(fmaxf(s0[3], s1[0]), s1[1]);
    float t2 = fmaxf(fmaxf(s1[2], s1[3]), s2[0]);
    float t3 = fmaxf(fmaxf(s2[1], s2[2]), s2[3]);
    float t4 = fmaxf(fmaxf(s3[0], s3[1]), s3[2]);
    float pmax = fmaxf(fmaxf(fmaxf(t0, t1), t2), fmaxf(fmaxf(t3, t4), s3[3]));

    if (!__all(pmax - m <= 8.f)) {
      float tm = fmaxf(pmax, __shfl_xor(pmax, 16));
      tm = fmaxf(tm, __shfl_xor(tm, 32));
      float mn = fmaxf(m, tm);
      float f = __builtin_amdgcn_exp2f(m - mn);
      sp *= f;
#pragma unroll
      for (int r = 0; r < 4; ++r) { acc0[r] *= f; acc1[r] *= f; }
      m = mn;
    }

    float p0[4], p1[4], p2[4], p3[4];
#pragma unroll
    for (int r = 0; r < 4; ++r) {
      p0[r] = __builtin_amdgcn_exp2f(s0[r] - m);
      p1[r] = __builtin_amdgcn_exp2f(s1[r] - m);
      p2[r] = __builtin_amdgcn_exp2f(s2[r] - m);
      p3[r] = __builtin_amdgcn_exp2f(s3[r] - m);
    }
    sp += ((p0[0] + p0[1]) + (p0[2] + p0[3])) + ((p1[0] + p1[1]) + (p1[2] + p1[3])) +
          ((p2[0] + p2[1]) + (p2[2] + p2[3])) + ((p3[0] + p3[1]) + (p3[2] + p3[3]));

#if HAVE_MFMA16
#pragma unroll
    for (int c = 0; c < 4; ++c) {
      const float* pc = (c == 0) ? p0 : (c == 1) ? p1 : (c == 2) ? p2 : p3;
      union { uint32_t u[2]; short4v v; } pk;
      pk.u[0] = cvtpk(pc[0], pc[1]);
      pk.u[1] = cvtpk(pc[2], pc[3]);
      const int kc = 2 * c + (g >> 1);
      const int pA = (kc + lo) & 7;
      const int pB = (kc + lo + 16) & 7;
      short4v va = *(const short4v*)(Vb + lo * 64 + pA * 8 + (g & 1) * 4);
      short4v vb = *(const short4v*)(Vb + (lo + 16) * 64 + pB * 8 + (g & 1) * 4);
      acc0 = __builtin_amdgcn_mfma_f32_16x16x16bf16_1k(va, pk.v, acc0, 0, 0, 0);
      acc1 = __builtin_amdgcn_mfma_f32_16x16x16bf16_1k(vb, pk.v, acc1, 0, 0, 0);
    }
#else
    uint32_t u0 = cvtpk(p0[0], p0[1]), u1 = cvtpk(p0[2], p0[3]);
    uint32_t u2 = cvtpk(p1[0], p1[1]), u3 = cvtpk(p1[2], p1[3]);
    uint32_t u4 = cvtpk(p2[0], p2[1]), u5 = cvtpk(p2[2], p2[3]);
    uint32_t u6 = cvtpk(p3[0], p3[1]), u7 = cvtpk(p3[2], p3[3]);
    union { uint32_t u[4]; short8 v; } pfa, pfb;
    {
      uint32_t x0 = (uint32_t)__shfl((int)u0, srcA), x2 = (uint32_t)__shfl((int)u2, srcA);
      uint32_t x1 = (uint32_t)__shfl((int)u1, srcA), x3 = (uint32_t)__shfl((int)u3, srcA);
      uint32_t y0 = (uint32_t)__shfl((int)u0, srcB), y2 = (uint32_t)__shfl((int)u2, srcB);
      uint32_t y1 = (uint32_t)__shfl((int)u1, srcB), y3 = (uint32_t)__shfl((int)u3, srcB);
      pfa.u[0] = (g < 2) ? x0 : x2;
      pfa.u[1] = (g < 2) ? x1 : x3;
      pfa.u[2] = (g < 2) ? y0 : y2;
      pfa.u[3] = (g < 2) ? y1 : y3;
    }
    {
      uint32_t x4 = (uint32_t)__shfl((int)u4, srcA), x6 = (uint32_t)__shfl((int)u6, srcA);
      uint32_t x5 = (uint32_t)__shfl((int)u5, srcA), x7 = (uint32_t)__shfl((int)u7, srcA);
      uint32_t y4 = (uint32_t)__shfl((int)u4, srcB), y6 = (uint32_t)__shfl((int)u6, srcB);
      uint32_t y5 = (uint32_t)__shfl((int)u5, srcB), y7 = (uint32_t)__shfl((int)u7, srcB);
      pfb.u[0] = (g < 2) ? x4 : x6;
      pfb.u[1] = (g < 2) ? x5 : x7;
      pfb.u[2] = (g < 2) ? y4 : y6;
      pfb.u[3] = (g < 2) ? y5 : y7;
    }
    short8 v0a = *(const short8*)(Vb + lo * 64 + vA);
    short8 v1a = *(const short8*)(Vb + (lo + 16) * 64 + vA);
    short8 v0b = *(const short8*)(Vb + lo * 64 + vB);
    short8 v1b = *(const short8*)(Vb + (lo + 16) * 64 + vB);
    acc0 = __builtin_amdgcn_mfma_f32_16x16x32_bf16(v0a, pfa.v, acc0, 0, 0, 0);
    acc1 = __builtin_amdgcn_mfma_f32_16x16x32_bf16(v1a, pfa.v, acc1, 0, 0, 0);
    acc0 = __builtin_amdgcn_mfma_f32_16x16x32_bf16(v0b, pfb.v, acc0, 0, 0, 0);
    acc1 = __builtin_amdgcn_mfma_f32_16x16x32_bf16(v1b, pfb.v, acc1, 0, 0, 0);
#endif

    asm volatile("s_waitcnt vmcnt(0)" ::: "memory"); // drain prefetch before barrier
    __syncthreads();
    buf ^= 1;
  }
  float s = sp;
  s += __shfl_xor(s, 16);
  s += __shfl_xor(s, 32);

  const size_t qidx = ((size_t)((half * 2 + b) * 16 + h)) * 2048 + q0 + lo;
  float* pacc = Pacc + qidx * 32;
  *(floatx4*)(pacc + 4 * g) = acc0;
  *(floatx4*)(pacc + 16 + 4 * g) = acc1;
  if (g == 0) Pms[qidx] = make_float2(m, s);
}

// ---------------- combine kv-split halves -> O32 (bf16) ----------------
__global__ __launch_bounds__(256) void combine_k(const float* __restrict__ Pacc,
                                                 const float2* __restrict__ Pms,
                                                 uint16_t* __restrict__ O32) {
  const int t = blockIdx.x * 256 + threadIdx.x; // 524288 threads
  const int f4 = t & 7;
  const int qq = (t >> 3) & 2047;
  const int h = (t >> 14) & 15;
  const int b = t >> 18;
  const size_t qidx0 = ((size_t)((0 + b) * 16 + h)) * 2048 + qq;
  const size_t qidx1 = ((size_t)((2 + b) * 16 + h)) * 2048 + qq;
  float2 ms0 = Pms[qidx0], ms1 = Pms[qidx1];
  float M = fmaxf(ms0.x, ms1.x);
  float w0 = __builtin_amdgcn_exp2f(ms0.x - M);
  float w1 = __builtin_amdgcn_exp2f(ms1.x - M);
  float inv = 1.0f / (ms0.y * w0 + ms1.y * w1);
  w0 *= inv; w1 *= inv;
  float4 a0 = *(const float4*)(Pacc + qidx0 * 32 + f4 * 4);
  float4 a1 = *(const float4*)(Pacc + qidx1 * 32 + f4 * 4);
  union { uint16_t u[4]; uint64_t q; } o;
  o.u[0] = f2bf(a0.x * w0 + a1.x * w1);
  o.u[1] = f2bf(a0.y * w0 + a1.y * w1);
  o.u[2] = f2bf(a0.z * w0 + a1.z * w1);
  o.u[3] = f2bf(a0.w * w0 + a1.w * w1);
  *(uint64_t*)(O32 + ((size_t)(b * 2048 + qq)) * 512 + h * 32 + f4 * 4) = o.q;
}

// ---------------- launch ----------------
extern "C" void kernel_launch(void* const* d_in, const int* in_sizes, int n_in,
                              void* d_out, int out_size, void* d_ws, size_t ws_size,
                              hipStream_t stream) {
  const float* q    = (const float*)d_in[0];
  const float* kv   = (const float*)d_in[1];
  const float* mask = (const float*)d_in[2];
  const float* Wq   = (const float*)d_in[3];
  const float* Wk   = (const float*)d_in[4];
  const float* Wv   = (const float*)d_in[5];
  const float* Wo   = (const float*)d_in[6];

  char* ws = (char*)d_ws;
  uint16_t* qb    = (uint16_t*)(ws);                  // 16 MB
  uint16_t* kvb   = (uint16_t*)(ws + (16ull << 20));  // 16 MB
  uint16_t* Qf    = (uint16_t*)(ws + (32ull << 20));  // 4 MB
  uint16_t* XK    = (uint16_t*)(ws + (36ull << 20));  // 4 MB
  uint16_t* VT    = (uint16_t*)(ws + (40ull << 20));  // 8 MB
  uint16_t* O32   = (uint16_t*)(ws + (48ull << 20));  // 4 MB
  uint16_t* WqFT  = (uint16_t*)(ws + (52ull << 20));  // 2 MB
  uint16_t* WkvT  = (uint16_t*)(ws + (54ull << 20));  // 4 MB
  uint16_t* WoFT  = (uint16_t*)(ws + (58ull << 20));  // 2 MB
  uint32_t* flag  = (uint32_t*)(ws + (60ull << 20));
  float*    Pacc  = (float*)(ws);                     // 16 MB, overlaps qb (dead by attn)
  float2*   Pms   = (float2*)(ws + (16ull << 20));    // 1 MB, overlaps kvb (dead by attn)

  const float SCALE2 = 0.08838834764831845f * 1.4426950408889634f;

  hipMemsetAsync(flag, 1, 4, stream); // 0x01010101 != 0 -> "trivial" until proven otherwise
  prep_k<<<22528, 256, 0, stream>>>(q, kv, mask, Wq, Wk, Wv, Wo,
                                    qb, kvb, WqFT, WkvT, WoFT, flag);
  proj_k<<<768, 256, 0, stream>>>(qb, kvb, WqFT, WkvT, Qf, XK, VT, SCALE2);
  attn_k<<<2048, 256, 0, stream>>>(Qf, XK, VT, mask, flag, Pacc, Pms);
  combine_k<<<2048, 256, 0, stream>>>(Pacc, Pms, O32);
  oproj_k<<<1024, 256, 0, stream>>>(O32, WoFT, (float*)d_out);
}